// Round 1
// baseline (215.381 us; speedup 1.0000x reference)
//
#include <hip/hip_runtime.h>
#include <math.h>

// ---------------------------------------------------------------------------
// FraudDetectionHybrid: 4-qubit statevector sim, algebraically collapsed.
//   encoder -> product state (per-wire 2-vectors)
//   RandomLayer + trainable block -> fixed 16x16 unitary U_post (built once
//   per launch by kernel A, which replicates numpy RandomState(42) exactly)
//   measure <Z_w> -> sign-sums of |U_post s|^2
//   BatchNorm(batch stats) + Linear -> out[b] = sum_w alpha_w ez[b,w] + c0
// ---------------------------------------------------------------------------

// ============================ MT19937 (numpy legacy) ========================
struct MT19937 {
  unsigned int mt[624];
  int pos;
};

__device__ void mt_init(MT19937& s, unsigned int seed) {
  s.mt[0] = seed;
  for (int i = 1; i < 624; ++i)
    s.mt[i] = 1812433253u * (s.mt[i - 1] ^ (s.mt[i - 1] >> 30)) + (unsigned int)i;
  s.pos = 624;
}

__device__ unsigned int mt_next(MT19937& s) {
  if (s.pos >= 624) {
    for (int i = 0; i < 624; ++i) {
      unsigned int y = (s.mt[i] & 0x80000000u) | (s.mt[(i + 1) % 624] & 0x7fffffffu);
      unsigned int v = s.mt[(i + 397) % 624] ^ (y >> 1);
      if (y & 1u) v ^= 0x9908b0dfu;
      s.mt[i] = v;
    }
    s.pos = 0;
  }
  unsigned int y = s.mt[s.pos++];
  y ^= y >> 11;
  y ^= (y << 7) & 0x9d2c5680u;
  y ^= (y << 15) & 0xefc60000u;
  y ^= y >> 18;
  return y;
}

// ============================ Kernel A: build U_post ========================
// kinds: 0=RX 1=RY 2=RZ 3=CNOT(w0=ctrl,w1=tgt) 4=CRX(w0=ctrl,w1=tgt) 5=H 6=SX
__global__ __launch_bounds__(64) void build_u_kernel(
    const float* __restrict__ rand_params, const float* __restrict__ rx0,
    const float* __restrict__ ry0, const float* __restrict__ rz0,
    const float* __restrict__ crx0, float2* __restrict__ U_out) {
  __shared__ int gk[64], gw0[64], gw1[64];
  __shared__ float gth[64];
  __shared__ int ng_s;

  if (threadIdx.x == 0) {
    MT19937 rng;
    mt_init(rng, 42u);
    int ng = 0, p = 0;
    for (int op = 0; op < 50; ++op) {
      unsigned int k = mt_next(rng) & 3u;  // randint(4): one 32-bit draw, mask 3
      if (k < 3u) {
        unsigned int w = mt_next(rng) & 3u;  // randint(4) wire
        gk[ng] = (int)k; gw0[ng] = (int)w; gw1[ng] = 0;
        gth[ng] = rand_params[p++];
        ++ng;
      } else {
        // choice(4,2,replace=False) == permutation(4)[:2] (Fisher-Yates desc.)
        int arr[4] = {0, 1, 2, 3};
        { unsigned int j = mt_next(rng) & 3u;            // i=3: mask 3, no reject
          int t = arr[3]; arr[3] = arr[j]; arr[j] = t; }
        { unsigned int j;                                // i=2: mask 3, reject >2
          do { j = mt_next(rng) & 3u; } while (j > 2u);
          int t = arr[2]; arr[2] = arr[j]; arr[j] = t; }
        { unsigned int j = mt_next(rng) & 1u;            // i=1: mask 1
          int t = arr[1]; arr[1] = arr[j]; arr[j] = t; }
        gk[ng] = 3; gw0[ng] = arr[0]; gw1[ng] = arr[1]; gth[ng] = 0.f;
        ++ng;
      }
    }
    // trainable block
    gk[ng] = 0; gw0[ng] = 0; gw1[ng] = 0; gth[ng] = rx0[0]; ++ng;   // RX w0
    gk[ng] = 1; gw0[ng] = 1; gw1[ng] = 0; gth[ng] = ry0[0]; ++ng;   // RY w1
    gk[ng] = 2; gw0[ng] = 3; gw1[ng] = 0; gth[ng] = rz0[0]; ++ng;   // RZ w3
    gk[ng] = 4; gw0[ng] = 0; gw1[ng] = 2; gth[ng] = crx0[0]; ++ng;  // CRX (0,2)
    gk[ng] = 5; gw0[ng] = 3; gw1[ng] = 0; gth[ng] = 0.f; ++ng;      // H w3
    gk[ng] = 6; gw0[ng] = 2; gw1[ng] = 0; gth[ng] = 0.f; ++ng;      // SX w2
    gk[ng] = 3; gw0[ng] = 3; gw1[ng] = 0; gth[ng] = 0.f; ++ng;      // CNOT (3,0)
    ng_s = ng;
  }
  __syncthreads();

  int col = threadIdx.x;
  if (col < 16) {
    float sx[16], sy[16];
    for (int i = 0; i < 16; ++i) { sx[i] = (i == col) ? 1.f : 0.f; sy[i] = 0.f; }
    int ng = ng_s;
    for (int g = 0; g < ng; ++g) {
      int kind = gk[g], w0 = gw0[g], w1 = gw1[g];
      float th = gth[g];
      if (kind == 3) {
        int cb = 8 >> w0, tb = 8 >> w1;  // wire0 = MSB (bit 3)
        for (int i = 0; i < 16; ++i) {
          if ((i & cb) && !(i & tb)) {
            int j = i | tb;
            float tx = sx[i], ty = sy[i];
            sx[i] = sx[j]; sy[i] = sy[j];
            sx[j] = tx; sy[j] = ty;
          }
        }
      } else {
        float u00x, u00y, u01x, u01y, u10x, u10y, u11x, u11y;
        if (kind == 0 || kind == 4) {        // RX
          float c = cosf(0.5f * th), s = sinf(0.5f * th);
          u00x = c; u00y = 0; u01x = 0; u01y = -s;
          u10x = 0; u10y = -s; u11x = c; u11y = 0;
        } else if (kind == 1) {              // RY
          float c = cosf(0.5f * th), s = sinf(0.5f * th);
          u00x = c; u00y = 0; u01x = -s; u01y = 0;
          u10x = s; u10y = 0; u11x = c; u11y = 0;
        } else if (kind == 2) {              // RZ
          float c = cosf(0.5f * th), s = sinf(0.5f * th);
          u00x = c; u00y = -s; u01x = 0; u01y = 0;
          u10x = 0; u10y = 0; u11x = c; u11y = s;
        } else if (kind == 5) {              // H
          float r = 0.70710678118654752f;
          u00x = r; u00y = 0; u01x = r; u01y = 0;
          u10x = r; u10y = 0; u11x = -r; u11y = 0;
        } else {                             // SX
          u00x = 0.5f; u00y = 0.5f; u01x = 0.5f; u01y = -0.5f;
          u10x = 0.5f; u10y = -0.5f; u11x = 0.5f; u11y = 0.5f;
        }
        int tb = 8 >> w0;
        int cb = 0;
        if (kind == 4) { cb = 8 >> w0; tb = 8 >> w1; }
        for (int i = 0; i < 16; ++i) {
          if (i & tb) continue;
          if (kind == 4 && !(i & cb)) continue;
          int j = i | tb;
          float ax = sx[i], ay = sy[i], bx = sx[j], by = sy[j];
          sx[i] = u00x * ax - u00y * ay + u01x * bx - u01y * by;
          sy[i] = u00x * ay + u00y * ax + u01x * by + u01y * bx;
          sx[j] = u10x * ax - u10y * ay + u11x * bx - u11y * by;
          sy[j] = u10x * ay + u10y * ax + u11x * by + u11y * bx;
        }
      }
    }
    for (int i = 0; i < 16; ++i) U_out[i * 16 + col] = make_float2(sx[i], sy[i]);
  }
}

// ===================== per-element ez (shared device fn) ====================
__device__ __forceinline__ void compute_ez(const float* __restrict__ features,
                                           long long b,
                                           const float2* __restrict__ Uld,
                                           float ez[4]) {
  const float4* fp = (const float4*)(features + b * 16);
  float4 F0 = fp[0], F1 = fp[1], F2 = fp[2], F3 = fp[3];
  float L0[4] = {F0.x, F0.y, F0.z, F0.w};
  float L1[4] = {F1.x, F1.y, F1.z, F1.w};
  float L2[4] = {F2.x, F2.y, F2.z, F2.w};
  float L3[4] = {F3.x, F3.y, F3.z, F3.w};
  float vax[4], vay[4], vbx[4], vby[4];
#pragma unroll
  for (int w = 0; w < 4; ++w) {
    // per-wire |0> column of RY(L3) RX(L2) RZ(L1) RY(L0)
    float s0, c0; __sincosf(0.5f * L0[w], &s0, &c0);
    float s1, c1; __sincosf(0.5f * L1[w], &s1, &c1);
    float s2, c2; __sincosf(0.5f * L2[w], &s2, &c2);
    float s3, c3; __sincosf(0.5f * L3[w], &s3, &c3);
    float ax = c0 * c1, ay = -c0 * s1;       // after RZ
    float bx = s0 * c1, by = s0 * s1;
    float a2x = c2 * ax + s2 * by, a2y = c2 * ay - s2 * bx;   // after RX
    float b2x = s2 * ay + c2 * bx, b2y = -s2 * ax + c2 * by;
    vax[w] = c3 * a2x - s3 * b2x; vay[w] = c3 * a2y - s3 * b2y;  // after RY
    vbx[w] = s3 * a2x + c3 * b2x; vby[w] = s3 * a2y + c3 * b2y;
  }
  // s = v0 (x) v1 (x) v2 (x) v3, wire0 = MSB
  float t01x[4], t01y[4], t23x[4], t23y[4];
  t01x[0] = vax[0] * vax[1] - vay[0] * vay[1]; t01y[0] = vax[0] * vay[1] + vay[0] * vax[1];
  t01x[1] = vax[0] * vbx[1] - vay[0] * vby[1]; t01y[1] = vax[0] * vby[1] + vay[0] * vbx[1];
  t01x[2] = vbx[0] * vax[1] - vby[0] * vay[1]; t01y[2] = vbx[0] * vay[1] + vby[0] * vax[1];
  t01x[3] = vbx[0] * vbx[1] - vby[0] * vby[1]; t01y[3] = vbx[0] * vby[1] + vby[0] * vbx[1];
  t23x[0] = vax[2] * vax[3] - vay[2] * vay[3]; t23y[0] = vax[2] * vay[3] + vay[2] * vax[3];
  t23x[1] = vax[2] * vbx[3] - vay[2] * vby[3]; t23y[1] = vax[2] * vby[3] + vay[2] * vbx[3];
  t23x[2] = vbx[2] * vax[3] - vby[2] * vay[3]; t23y[2] = vbx[2] * vay[3] + vby[2] * vax[3];
  t23x[3] = vbx[2] * vbx[3] - vby[2] * vby[3]; t23y[3] = vbx[2] * vby[3] + vby[2] * vbx[3];
  float sx[16], sy[16];
#pragma unroll
  for (int i = 0; i < 16; ++i) {
    int a = i >> 2, c = i & 3;
    sx[i] = t01x[a] * t23x[c] - t01y[a] * t23y[c];
    sy[i] = t01x[a] * t23y[c] + t01y[a] * t23x[c];
  }
  // s' = U_post s ; ez_w = sum_i sign(i,w) |s'_i|^2
  float e0 = 0.f, e1 = 0.f, e2 = 0.f, e3 = 0.f;
#pragma unroll
  for (int i = 0; i < 16; ++i) {
    float ax = 0.f, ay = 0.f;
#pragma unroll
    for (int j = 0; j < 16; ++j) {
      float2 u = Uld[i * 16 + j];
      ax += u.x * sx[j] - u.y * sy[j];
      ay += u.x * sy[j] + u.y * sx[j];
    }
    float p = ax * ax + ay * ay;
    e0 += (i & 8) ? -p : p;
    e1 += (i & 4) ? -p : p;
    e2 += (i & 2) ? -p : p;
    e3 += (i & 1) ? -p : p;
  }
  ez[0] = e0; ez[1] = e1; ez[2] = e2; ez[3] = e3;
}

// ===================== Kernel B: ez + block partial sums ====================
__global__ __launch_bounds__(256) void main_pass_kernel(
    const float* __restrict__ features, const float2* __restrict__ U,
    float* __restrict__ ez_out, float* __restrict__ partials, int B, int useEz) {
  __shared__ float2 ldsU[256];
  ldsU[threadIdx.x] = U[threadIdx.x];
  __syncthreads();

  long long b = (long long)blockIdx.x * 256 + threadIdx.x;
  float ez[4] = {0.f, 0.f, 0.f, 0.f};
  if (b < B) {
    compute_ez(features, b, ldsU, ez);
    if (useEz) ((float4*)ez_out)[b] = make_float4(ez[0], ez[1], ez[2], ez[3]);
  }
  float q[8] = {ez[0], ez[1], ez[2], ez[3],
                ez[0] * ez[0], ez[1] * ez[1], ez[2] * ez[2], ez[3] * ez[3]};
#pragma unroll
  for (int off = 32; off; off >>= 1)
#pragma unroll
    for (int k = 0; k < 8; ++k) q[k] += __shfl_down(q[k], off, 64);
  __shared__ float wred[4][8];
  int lane = threadIdx.x & 63, wv = threadIdx.x >> 6;
  if (lane == 0)
    for (int k = 0; k < 8; ++k) wred[wv][k] = q[k];
  __syncthreads();
  if (threadIdx.x == 0) {
    for (int k = 0; k < 8; ++k)
      partials[(size_t)blockIdx.x * 8 + k] =
          wred[0][k] + wred[1][k] + wred[2][k] + wred[3][k];
  }
}

// ================= Kernel C: reduce partials -> alpha, c0 ===================
__global__ __launch_bounds__(256) void stats_kernel(
    const float* __restrict__ partials, int nblk, const float* __restrict__ gamma,
    const float* __restrict__ beta, const float* __restrict__ W,
    const float* __restrict__ bias, float* __restrict__ coef, float invB) {
  float q[8] = {0.f, 0.f, 0.f, 0.f, 0.f, 0.f, 0.f, 0.f};
  for (int idx = threadIdx.x; idx < nblk; idx += 256)
    for (int k = 0; k < 8; ++k) q[k] += partials[(size_t)idx * 8 + k];
#pragma unroll
  for (int off = 32; off; off >>= 1)
#pragma unroll
    for (int k = 0; k < 8; ++k) q[k] += __shfl_down(q[k], off, 64);
  __shared__ float wred[4][8];
  int lane = threadIdx.x & 63, wv = threadIdx.x >> 6;
  if (lane == 0)
    for (int k = 0; k < 8; ++k) wred[wv][k] = q[k];
  __syncthreads();
  if (threadIdx.x == 0) {
    float c0 = bias[0];
    for (int w = 0; w < 4; ++w) {
      float Sw = wred[0][w] + wred[1][w] + wred[2][w] + wred[3][w];
      float Qw = wred[0][4 + w] + wred[1][4 + w] + wred[2][4 + w] + wred[3][4 + w];
      float mu = Sw * invB;
      float var = Qw * invB - mu * mu;
      float inv = rsqrtf(var + 1e-5f);
      coef[w] = W[w] * gamma[w] * inv;
      c0 += W[w] * (beta[w] - gamma[w] * mu * inv);
    }
    coef[4] = c0;
  }
}

// ======================= Kernel D: final output pass ========================
__global__ __launch_bounds__(256) void final_pass_kernel(
    const float* __restrict__ features, const float2* __restrict__ U,
    const float* __restrict__ ez_in, const float* __restrict__ coef,
    float* __restrict__ out, int B, int useEz) {
  __shared__ float2 ldsU[256];
  ldsU[threadIdx.x] = U[threadIdx.x];
  __syncthreads();

  long long b = (long long)blockIdx.x * 256 + threadIdx.x;
  if (b >= B) return;
  float ez[4];
  if (useEz) {
    float4 e = ((const float4*)ez_in)[b];
    ez[0] = e.x; ez[1] = e.y; ez[2] = e.z; ez[3] = e.w;
  } else {
    compute_ez(features, b, ldsU, ez);
  }
  out[b] = coef[4] + coef[0] * ez[0] + coef[1] * ez[1] + coef[2] * ez[2] +
           coef[3] * ez[3];
}

// ================================ launch ====================================
extern "C" void kernel_launch(void* const* d_in, const int* in_sizes, int n_in,
                              void* d_out, int out_size, void* d_ws, size_t ws_size,
                              hipStream_t stream) {
  const float* features    = (const float*)d_in[0];
  const float* rand_params = (const float*)d_in[1];
  const float* rx0         = (const float*)d_in[2];
  const float* ry0         = (const float*)d_in[3];
  const float* rz0         = (const float*)d_in[4];
  const float* crx0        = (const float*)d_in[5];
  const float* gamma       = (const float*)d_in[6];
  const float* beta        = (const float*)d_in[7];
  const float* W           = (const float*)d_in[8];
  const float* bias        = (const float*)d_in[9];
  float* out = (float*)d_out;

  int B = in_sizes[0] / 16;
  int nblk = (B + 255) / 256;

  char* ws = (char*)d_ws;
  float2* U = (float2*)ws;                                   // 2048 B
  float* partials = (float*)(ws + 2048);                     // nblk*32 B
  float* coef = (float*)(ws + 2048 + (size_t)nblk * 32);     // 32 B
  size_t ez_off = (2048 + (size_t)nblk * 32 + 32 + 255) & ~(size_t)255;
  float* ez = (float*)(ws + ez_off);
  int useEz = (ws_size >= ez_off + (size_t)B * 16) ? 1 : 0;

  build_u_kernel<<<1, 64, 0, stream>>>(rand_params, rx0, ry0, rz0, crx0, U);
  main_pass_kernel<<<nblk, 256, 0, stream>>>(features, U, ez, partials, B, useEz);
  stats_kernel<<<1, 256, 0, stream>>>(partials, nblk, gamma, beta, W, bias, coef,
                                      1.0f / (float)B);
  final_pass_kernel<<<nblk, 256, 0, stream>>>(features, U, ez, coef, out, B, useEz);
}

// Round 2
// 109.947 us; speedup vs baseline: 1.9590x; 1.9590x over previous
//
#include <hip/hip_runtime.h>
#include <math.h>

// ---------------------------------------------------------------------------
// FraudDetectionHybrid: 4-qubit statevector sim, algebraically collapsed.
//   encoder -> product state (per-wire 2-vectors)           [device, per-elem]
//   RandomLayer + trainable block -> fixed 16x16 unitary    [gate seq on HOST,
//     U_post built on device by a tiny 1-wave kernel]
//   measure <Z_w> -> sign-sums of |U_post s|^2
//   BatchNorm(batch stats) + Linear -> out[b] = sum_w a_w ez[b,w] + c0
//
// R1 lesson: MT19937 on device put mt[624] in scratch and ran a serial
// dependent chain -> 240us. The gate sequence depends only on seed 42, so
// derive it on the host each call (deterministic) and pass by value.
// ---------------------------------------------------------------------------

struct GateList {
  signed char kind[64];   // 0=RX 1=RY 2=RZ 3=CNOT 4=CRX 5=H 6=SX
  signed char w0[64];
  signed char w1[64];
  signed char pidx[64];   // >=0: rand_params idx; -1 none; -2 rx0; -3 ry0; -4 rz0; -5 crx0
  int ng;
};

// ====================== host-side numpy RandomState(42) =====================
namespace {
struct HostMT {
  unsigned int mt[624];
  int pos;
};
static void h_mt_init(HostMT& s, unsigned int seed) {
  s.mt[0] = seed;
  for (int i = 1; i < 624; ++i)
    s.mt[i] = 1812433253u * (s.mt[i - 1] ^ (s.mt[i - 1] >> 30)) + (unsigned int)i;
  s.pos = 624;
}
static unsigned int h_mt_next(HostMT& s) {
  if (s.pos >= 624) {
    for (int i = 0; i < 624; ++i) {
      unsigned int y = (s.mt[i] & 0x80000000u) | (s.mt[(i + 1) % 624] & 0x7fffffffu);
      unsigned int v = s.mt[(i + 397) % 624] ^ (y >> 1);
      if (y & 1u) v ^= 0x9908b0dfu;
      s.mt[i] = v;
    }
    s.pos = 0;
  }
  unsigned int y = s.mt[s.pos++];
  y ^= y >> 11;
  y ^= (y << 7) & 0x9d2c5680u;
  y ^= (y << 15) & 0xefc60000u;
  y ^= y >> 18;
  return y;
}
static GateList build_gate_list() {
  GateList gl;
  HostMT rng;
  h_mt_init(rng, 42u);
  int ng = 0, p = 0;
  for (int op = 0; op < 50; ++op) {
    unsigned int k = h_mt_next(rng) & 3u;     // randint(4): one draw, mask 3
    if (k < 3u) {
      unsigned int w = h_mt_next(rng) & 3u;   // wire
      gl.kind[ng] = (signed char)k; gl.w0[ng] = (signed char)w; gl.w1[ng] = 0;
      gl.pidx[ng] = (signed char)(p++);
      ++ng;
    } else {
      // choice(4,2,replace=False): Fisher-Yates descending, mask-rejection
      int arr[4] = {0, 1, 2, 3};
      { unsigned int j = h_mt_next(rng) & 3u;
        int t = arr[3]; arr[3] = arr[j]; arr[j] = t; }
      { unsigned int j;
        do { j = h_mt_next(rng) & 3u; } while (j > 2u);
        int t = arr[2]; arr[2] = arr[j]; arr[j] = t; }
      { unsigned int j = h_mt_next(rng) & 1u;
        int t = arr[1]; arr[1] = arr[j]; arr[j] = t; }
      gl.kind[ng] = 3; gl.w0[ng] = (signed char)arr[0];
      gl.w1[ng] = (signed char)arr[1]; gl.pidx[ng] = -1;
      ++ng;
    }
  }
  // trainable block
  gl.kind[ng] = 0; gl.w0[ng] = 0; gl.w1[ng] = 0; gl.pidx[ng] = -2; ++ng; // RX w0
  gl.kind[ng] = 1; gl.w0[ng] = 1; gl.w1[ng] = 0; gl.pidx[ng] = -3; ++ng; // RY w1
  gl.kind[ng] = 2; gl.w0[ng] = 3; gl.w1[ng] = 0; gl.pidx[ng] = -4; ++ng; // RZ w3
  gl.kind[ng] = 4; gl.w0[ng] = 0; gl.w1[ng] = 2; gl.pidx[ng] = -5; ++ng; // CRX(0,2)
  gl.kind[ng] = 5; gl.w0[ng] = 3; gl.w1[ng] = 0; gl.pidx[ng] = -1; ++ng; // H w3
  gl.kind[ng] = 6; gl.w0[ng] = 2; gl.w1[ng] = 0; gl.pidx[ng] = -1; ++ng; // SX w2
  gl.kind[ng] = 3; gl.w0[ng] = 3; gl.w1[ng] = 0; gl.pidx[ng] = -1; ++ng; // CNOT(3,0)
  gl.ng = ng;
  return gl;
}
}  // namespace

// ============================ Kernel A: build U_post ========================
__global__ __launch_bounds__(64) void build_u_kernel(
    GateList gl, const float* __restrict__ rand_params,
    const float* __restrict__ rx0, const float* __restrict__ ry0,
    const float* __restrict__ rz0, const float* __restrict__ crx0,
    float2* __restrict__ U_out) {
  __shared__ float theta_s[64];
  int t = threadIdx.x;
  if (t < gl.ng) {
    int pi = gl.pidx[t];
    float th = 0.f;
    if (pi >= 0)       th = rand_params[pi];
    else if (pi == -2) th = rx0[0];
    else if (pi == -3) th = ry0[0];
    else if (pi == -4) th = rz0[0];
    else if (pi == -5) th = crx0[0];
    theta_s[t] = th;
  }
  __syncthreads();

  int col = threadIdx.x;
  if (col >= 16) return;
  float sx[16], sy[16];
#pragma unroll
  for (int i = 0; i < 16; ++i) { sx[i] = (i == col) ? 1.f : 0.f; sy[i] = 0.f; }
  int ng = gl.ng;
  for (int g = 0; g < ng; ++g) {
    int kind = gl.kind[g], w0 = gl.w0[g], w1 = gl.w1[g];
    float th = theta_s[g];
    if (kind == 3) {  // CNOT
      int cb = 8 >> w0, tb = 8 >> w1;  // wire0 = MSB (bit 3)
      for (int i = 0; i < 16; ++i) {
        if ((i & cb) && !(i & tb)) {
          int j = i | tb;
          float tx = sx[i], ty = sy[i];
          sx[i] = sx[j]; sy[i] = sy[j];
          sx[j] = tx; sy[j] = ty;
        }
      }
    } else {
      float u00x, u00y, u01x, u01y, u10x, u10y, u11x, u11y;
      if (kind == 0 || kind == 4) {        // RX / CRX
        float c = cosf(0.5f * th), s = sinf(0.5f * th);
        u00x = c; u00y = 0; u01x = 0; u01y = -s;
        u10x = 0; u10y = -s; u11x = c; u11y = 0;
      } else if (kind == 1) {              // RY
        float c = cosf(0.5f * th), s = sinf(0.5f * th);
        u00x = c; u00y = 0; u01x = -s; u01y = 0;
        u10x = s; u10y = 0; u11x = c; u11y = 0;
      } else if (kind == 2) {              // RZ
        float c = cosf(0.5f * th), s = sinf(0.5f * th);
        u00x = c; u00y = -s; u01x = 0; u01y = 0;
        u10x = 0; u10y = 0; u11x = c; u11y = s;
      } else if (kind == 5) {              // H
        float r = 0.70710678118654752f;
        u00x = r; u00y = 0; u01x = r; u01y = 0;
        u10x = r; u10y = 0; u11x = -r; u11y = 0;
      } else {                             // SX
        u00x = 0.5f; u00y = 0.5f; u01x = 0.5f; u01y = -0.5f;
        u10x = 0.5f; u10y = -0.5f; u11x = 0.5f; u11y = 0.5f;
      }
      int tb = 8 >> w0;
      int cb = 0;
      if (kind == 4) { cb = 8 >> w0; tb = 8 >> w1; }
      for (int i = 0; i < 16; ++i) {
        if (i & tb) continue;
        if (kind == 4 && !(i & cb)) continue;
        int j = i | tb;
        float ax = sx[i], ay = sy[i], bx = sx[j], by = sy[j];
        sx[i] = u00x * ax - u00y * ay + u01x * bx - u01y * by;
        sy[i] = u00x * ay + u00y * ax + u01x * by + u01y * bx;
        sx[j] = u10x * ax - u10y * ay + u11x * bx - u11y * by;
        sy[j] = u10x * ay + u10y * ax + u11x * by + u11y * bx;
      }
    }
  }
#pragma unroll
  for (int i = 0; i < 16; ++i) U_out[i * 16 + col] = make_float2(sx[i], sy[i]);
}

// ===================== per-element ez (shared device fn) ====================
__device__ __forceinline__ void compute_ez(const float* __restrict__ features,
                                           long long b,
                                           const float2* __restrict__ Uld,
                                           float ez[4]) {
  const float4* fp = (const float4*)(features + b * 16);
  float4 F0 = fp[0], F1 = fp[1], F2 = fp[2], F3 = fp[3];
  float L0[4] = {F0.x, F0.y, F0.z, F0.w};
  float L1[4] = {F1.x, F1.y, F1.z, F1.w};
  float L2[4] = {F2.x, F2.y, F2.z, F2.w};
  float L3[4] = {F3.x, F3.y, F3.z, F3.w};
  float vax[4], vay[4], vbx[4], vby[4];
#pragma unroll
  for (int w = 0; w < 4; ++w) {
    // per-wire |0> column of RY(L3) RX(L2) RZ(L1) RY(L0)
    float s0, c0; __sincosf(0.5f * L0[w], &s0, &c0);
    float s1, c1; __sincosf(0.5f * L1[w], &s1, &c1);
    float s2, c2; __sincosf(0.5f * L2[w], &s2, &c2);
    float s3, c3; __sincosf(0.5f * L3[w], &s3, &c3);
    float ax = c0 * c1, ay = -c0 * s1;       // after RZ
    float bx = s0 * c1, by = s0 * s1;
    float a2x = c2 * ax + s2 * by, a2y = c2 * ay - s2 * bx;   // after RX
    float b2x = s2 * ay + c2 * bx, b2y = -s2 * ax + c2 * by;
    vax[w] = c3 * a2x - s3 * b2x; vay[w] = c3 * a2y - s3 * b2y;  // after RY
    vbx[w] = s3 * a2x + c3 * b2x; vby[w] = s3 * a2y + c3 * b2y;
  }
  // s = v0 (x) v1 (x) v2 (x) v3, wire0 = MSB
  float t01x[4], t01y[4], t23x[4], t23y[4];
  t01x[0] = vax[0] * vax[1] - vay[0] * vay[1]; t01y[0] = vax[0] * vay[1] + vay[0] * vax[1];
  t01x[1] = vax[0] * vbx[1] - vay[0] * vby[1]; t01y[1] = vax[0] * vby[1] + vay[0] * vbx[1];
  t01x[2] = vbx[0] * vax[1] - vby[0] * vay[1]; t01y[2] = vbx[0] * vay[1] + vby[0] * vax[1];
  t01x[3] = vbx[0] * vbx[1] - vby[0] * vby[1]; t01y[3] = vbx[0] * vby[1] + vby[0] * vbx[1];
  t23x[0] = vax[2] * vax[3] - vay[2] * vay[3]; t23y[0] = vax[2] * vay[3] + vay[2] * vax[3];
  t23x[1] = vax[2] * vbx[3] - vay[2] * vby[3]; t23y[1] = vax[2] * vby[3] + vay[2] * vbx[3];
  t23x[2] = vbx[2] * vax[3] - vby[2] * vay[3]; t23y[2] = vbx[2] * vay[3] + vby[2] * vax[3];
  t23x[3] = vbx[2] * vbx[3] - vby[2] * vby[3]; t23y[3] = vbx[2] * vby[3] + vby[2] * vbx[3];
  float sx[16], sy[16];
#pragma unroll
  for (int i = 0; i < 16; ++i) {
    int a = i >> 2, c = i & 3;
    sx[i] = t01x[a] * t23x[c] - t01y[a] * t23y[c];
    sy[i] = t01x[a] * t23y[c] + t01y[a] * t23x[c];
  }
  // s' = U_post s ; ez_w = sum_i sign(i,w) |s'_i|^2
  float e0 = 0.f, e1 = 0.f, e2 = 0.f, e3 = 0.f;
#pragma unroll
  for (int i = 0; i < 16; ++i) {
    float ax = 0.f, ay = 0.f;
#pragma unroll
    for (int j = 0; j < 16; ++j) {
      float2 u = Uld[i * 16 + j];
      ax += u.x * sx[j] - u.y * sy[j];
      ay += u.x * sy[j] + u.y * sx[j];
    }
    float p = ax * ax + ay * ay;
    e0 += (i & 8) ? -p : p;
    e1 += (i & 4) ? -p : p;
    e2 += (i & 2) ? -p : p;
    e3 += (i & 1) ? -p : p;
  }
  ez[0] = e0; ez[1] = e1; ez[2] = e2; ez[3] = e3;
}

// ===================== Kernel B: ez + block partial sums ====================
__global__ __launch_bounds__(256) void main_pass_kernel(
    const float* __restrict__ features, const float2* __restrict__ U,
    float* __restrict__ ez_out, float* __restrict__ partials, int B, int useEz) {
  __shared__ float2 ldsU[256];
  ldsU[threadIdx.x] = U[threadIdx.x];
  __syncthreads();

  long long b = (long long)blockIdx.x * 256 + threadIdx.x;
  float ez[4] = {0.f, 0.f, 0.f, 0.f};
  if (b < B) {
    compute_ez(features, b, ldsU, ez);
    if (useEz) ((float4*)ez_out)[b] = make_float4(ez[0], ez[1], ez[2], ez[3]);
  }
  float q[8] = {ez[0], ez[1], ez[2], ez[3],
                ez[0] * ez[0], ez[1] * ez[1], ez[2] * ez[2], ez[3] * ez[3]};
#pragma unroll
  for (int off = 32; off; off >>= 1)
#pragma unroll
    for (int k = 0; k < 8; ++k) q[k] += __shfl_down(q[k], off, 64);
  __shared__ float wred[4][8];
  int lane = threadIdx.x & 63, wv = threadIdx.x >> 6;
  if (lane == 0)
    for (int k = 0; k < 8; ++k) wred[wv][k] = q[k];
  __syncthreads();
  if (threadIdx.x == 0) {
    for (int k = 0; k < 8; ++k)
      partials[(size_t)blockIdx.x * 8 + k] =
          wred[0][k] + wred[1][k] + wred[2][k] + wred[3][k];
  }
}

// ================= Kernel C: reduce partials -> alpha, c0 ===================
__global__ __launch_bounds__(256) void stats_kernel(
    const float* __restrict__ partials, int nblk, const float* __restrict__ gamma,
    const float* __restrict__ beta, const float* __restrict__ W,
    const float* __restrict__ bias, float* __restrict__ coef, float invB) {
  float q[8] = {0.f, 0.f, 0.f, 0.f, 0.f, 0.f, 0.f, 0.f};
  for (int idx = threadIdx.x; idx < nblk; idx += 256)
    for (int k = 0; k < 8; ++k) q[k] += partials[(size_t)idx * 8 + k];
#pragma unroll
  for (int off = 32; off; off >>= 1)
#pragma unroll
    for (int k = 0; k < 8; ++k) q[k] += __shfl_down(q[k], off, 64);
  __shared__ float wred[4][8];
  int lane = threadIdx.x & 63, wv = threadIdx.x >> 6;
  if (lane == 0)
    for (int k = 0; k < 8; ++k) wred[wv][k] = q[k];
  __syncthreads();
  if (threadIdx.x == 0) {
    float c0 = bias[0];
    for (int w = 0; w < 4; ++w) {
      float Sw = wred[0][w] + wred[1][w] + wred[2][w] + wred[3][w];
      float Qw = wred[0][4 + w] + wred[1][4 + w] + wred[2][4 + w] + wred[3][4 + w];
      float mu = Sw * invB;
      float var = Qw * invB - mu * mu;
      float inv = rsqrtf(var + 1e-5f);
      coef[w] = W[w] * gamma[w] * inv;
      c0 += W[w] * (beta[w] - gamma[w] * mu * inv);
    }
    coef[4] = c0;
  }
}

// ======================= Kernel D: final output pass ========================
__global__ __launch_bounds__(256) void final_pass_kernel(
    const float* __restrict__ features, const float2* __restrict__ U,
    const float* __restrict__ ez_in, const float* __restrict__ coef,
    float* __restrict__ out, int B, int useEz) {
  __shared__ float2 ldsU[256];
  if (!useEz) {
    ldsU[threadIdx.x] = U[threadIdx.x];
    __syncthreads();
  }
  long long b = (long long)blockIdx.x * 256 + threadIdx.x;
  if (b >= B) return;
  float ez[4];
  if (useEz) {
    float4 e = ((const float4*)ez_in)[b];
    ez[0] = e.x; ez[1] = e.y; ez[2] = e.z; ez[3] = e.w;
  } else {
    compute_ez(features, b, ldsU, ez);
  }
  out[b] = coef[4] + coef[0] * ez[0] + coef[1] * ez[1] + coef[2] * ez[2] +
           coef[3] * ez[3];
}

// ================================ launch ====================================
extern "C" void kernel_launch(void* const* d_in, const int* in_sizes, int n_in,
                              void* d_out, int out_size, void* d_ws, size_t ws_size,
                              hipStream_t stream) {
  const float* features    = (const float*)d_in[0];
  const float* rand_params = (const float*)d_in[1];
  const float* rx0         = (const float*)d_in[2];
  const float* ry0         = (const float*)d_in[3];
  const float* rz0         = (const float*)d_in[4];
  const float* crx0        = (const float*)d_in[5];
  const float* gamma       = (const float*)d_in[6];
  const float* beta        = (const float*)d_in[7];
  const float* W           = (const float*)d_in[8];
  const float* bias        = (const float*)d_in[9];
  float* out = (float*)d_out;

  int B = in_sizes[0] / 16;
  int nblk = (B + 255) / 256;

  char* ws = (char*)d_ws;
  float2* U = (float2*)ws;                                   // 2048 B
  float* partials = (float*)(ws + 2048);                     // nblk*32 B
  float* coef = (float*)(ws + 2048 + (size_t)nblk * 32);     // 32 B
  size_t ez_off = (2048 + (size_t)nblk * 32 + 32 + 255) & ~(size_t)255;
  float* ez = (float*)(ws + ez_off);
  int useEz = (ws_size >= ez_off + (size_t)B * 16) ? 1 : 0;

  GateList gl = build_gate_list();  // host-side, deterministic each call

  build_u_kernel<<<1, 64, 0, stream>>>(gl, rand_params, rx0, ry0, rz0, crx0, U);
  main_pass_kernel<<<nblk, 256, 0, stream>>>(features, U, ez, partials, B, useEz);
  stats_kernel<<<1, 256, 0, stream>>>(partials, nblk, gamma, beta, W, bias, coef,
                                      1.0f / (float)B);
  final_pass_kernel<<<nblk, 256, 0, stream>>>(features, U, ez, coef, out, B, useEz);
}

// Round 3
// 45.825 us; speedup vs baseline: 4.7001x; 2.3993x over previous
//
#include <hip/hip_runtime.h>
#include <math.h>

// ---------------------------------------------------------------------------
// FraudDetectionHybrid: 4-qubit statevector sim, algebraically collapsed.
//   encoder -> product state (per-wire 2-vectors)           [device, per-elem]
//   RandomLayer + trainable block -> fixed 16x16 unitary    [gate seq on HOST,
//     U_post built on device by a tiny 1-wave kernel]
//   measure <Z_w> -> sign-sums of |U_post s|^2
//   BatchNorm(batch stats) + Linear -> out[b] = sum_w a_w ez[b,w] + c0
//
// R1 lesson: MT19937 on device -> scratch serial chain (240us). Host now
//   derives the gate list (seed 42, deterministic) and passes it by value.
// R2 lesson: runtime-indexed sx[16]/sy[16] in build_u -> scratch again
//   (100us, VGPR=52, VALUBusy~0). All gate appliers are now templated on the
//   wire bit(s) with fully-unrolled static loops so amplitudes stay in VGPRs.
// ---------------------------------------------------------------------------

struct GateList {
  signed char kind[64];   // 0=RX 1=RY 2=RZ 3=CNOT 4=CRX 5=H 6=SX
  signed char w0[64];
  signed char w1[64];
  signed char pidx[64];   // >=0: rand_params idx; -1 none; -2 rx0; -3 ry0; -4 rz0; -5 crx0
  int ng;
};

// ====================== host-side numpy RandomState(42) =====================
namespace {
struct HostMT {
  unsigned int mt[624];
  int pos;
};
static void h_mt_init(HostMT& s, unsigned int seed) {
  s.mt[0] = seed;
  for (int i = 1; i < 624; ++i)
    s.mt[i] = 1812433253u * (s.mt[i - 1] ^ (s.mt[i - 1] >> 30)) + (unsigned int)i;
  s.pos = 624;
}
static unsigned int h_mt_next(HostMT& s) {
  if (s.pos >= 624) {
    for (int i = 0; i < 624; ++i) {
      unsigned int y = (s.mt[i] & 0x80000000u) | (s.mt[(i + 1) % 624] & 0x7fffffffu);
      unsigned int v = s.mt[(i + 397) % 624] ^ (y >> 1);
      if (y & 1u) v ^= 0x9908b0dfu;
      s.mt[i] = v;
    }
    s.pos = 0;
  }
  unsigned int y = s.mt[s.pos++];
  y ^= y >> 11;
  y ^= (y << 7) & 0x9d2c5680u;
  y ^= (y << 15) & 0xefc60000u;
  y ^= y >> 18;
  return y;
}
static GateList build_gate_list() {
  GateList gl;
  HostMT rng;
  h_mt_init(rng, 42u);
  int ng = 0, p = 0;
  for (int op = 0; op < 50; ++op) {
    unsigned int k = h_mt_next(rng) & 3u;     // randint(4): one draw, mask 3
    if (k < 3u) {
      unsigned int w = h_mt_next(rng) & 3u;   // wire
      gl.kind[ng] = (signed char)k; gl.w0[ng] = (signed char)w; gl.w1[ng] = 0;
      gl.pidx[ng] = (signed char)(p++);
      ++ng;
    } else {
      // choice(4,2,replace=False): Fisher-Yates descending, mask-rejection
      int arr[4] = {0, 1, 2, 3};
      { unsigned int j = h_mt_next(rng) & 3u;
        int t = arr[3]; arr[3] = arr[j]; arr[j] = t; }
      { unsigned int j;
        do { j = h_mt_next(rng) & 3u; } while (j > 2u);
        int t = arr[2]; arr[2] = arr[j]; arr[j] = t; }
      { unsigned int j = h_mt_next(rng) & 1u;
        int t = arr[1]; arr[1] = arr[j]; arr[j] = t; }
      gl.kind[ng] = 3; gl.w0[ng] = (signed char)arr[0];
      gl.w1[ng] = (signed char)arr[1]; gl.pidx[ng] = -1;
      ++ng;
    }
  }
  // trainable block
  gl.kind[ng] = 0; gl.w0[ng] = 0; gl.w1[ng] = 0; gl.pidx[ng] = -2; ++ng; // RX w0
  gl.kind[ng] = 1; gl.w0[ng] = 1; gl.w1[ng] = 0; gl.pidx[ng] = -3; ++ng; // RY w1
  gl.kind[ng] = 2; gl.w0[ng] = 3; gl.w1[ng] = 0; gl.pidx[ng] = -4; ++ng; // RZ w3
  gl.kind[ng] = 4; gl.w0[ng] = 0; gl.w1[ng] = 2; gl.pidx[ng] = -5; ++ng; // CRX(0,2)
  gl.kind[ng] = 5; gl.w0[ng] = 3; gl.w1[ng] = 0; gl.pidx[ng] = -1; ++ng; // H w3
  gl.kind[ng] = 6; gl.w0[ng] = 2; gl.w1[ng] = 0; gl.pidx[ng] = -1; ++ng; // SX w2
  gl.kind[ng] = 3; gl.w0[ng] = 3; gl.w1[ng] = 0; gl.pidx[ng] = -1; ++ng; // CNOT(3,0)
  gl.ng = ng;
  return gl;
}
}  // namespace

// ================= templated gate appliers (static indices) =================
// wire0 = MSB (bit 3): TB = 8 >> wire.

template <int TB>
__device__ __forceinline__ void ap_rx(float (&sx)[16], float (&sy)[16],
                                      float c, float s) {
#pragma unroll
  for (int i = 0; i < 16; ++i) {
    if (i & TB) continue;
    const int j = i | TB;
    float ax = sx[i], ay = sy[i], bx = sx[j], by = sy[j];
    sx[i] = c * ax + s * by;  sy[i] = c * ay - s * bx;   // a' = c a - i s b
    sx[j] = c * bx + s * ay;  sy[j] = c * by - s * ax;   // b' = -i s a + c b
  }
}

template <int TB>
__device__ __forceinline__ void ap_ry(float (&sx)[16], float (&sy)[16],
                                      float c, float s) {
#pragma unroll
  for (int i = 0; i < 16; ++i) {
    if (i & TB) continue;
    const int j = i | TB;
    float ax = sx[i], ay = sy[i], bx = sx[j], by = sy[j];
    sx[i] = c * ax - s * bx;  sy[i] = c * ay - s * by;   // a' = c a - s b
    sx[j] = s * ax + c * bx;  sy[j] = s * ay + c * by;   // b' = s a + c b
  }
}

template <int TB>
__device__ __forceinline__ void ap_rz(float (&sx)[16], float (&sy)[16],
                                      float c, float s) {
#pragma unroll
  for (int i = 0; i < 16; ++i) {
    if (i & TB) continue;
    const int j = i | TB;
    float ax = sx[i], ay = sy[i], bx = sx[j], by = sy[j];
    sx[i] = c * ax + s * ay;  sy[i] = c * ay - s * ax;   // a' = (c - i s) a
    sx[j] = c * bx - s * by;  sy[j] = c * by + s * bx;   // b' = (c + i s) b
  }
}

template <int TB>
__device__ __forceinline__ void ap_h(float (&sx)[16], float (&sy)[16]) {
  const float r = 0.70710678118654752f;
#pragma unroll
  for (int i = 0; i < 16; ++i) {
    if (i & TB) continue;
    const int j = i | TB;
    float ax = sx[i], ay = sy[i], bx = sx[j], by = sy[j];
    sx[i] = r * (ax + bx);  sy[i] = r * (ay + by);
    sx[j] = r * (ax - bx);  sy[j] = r * (ay - by);
  }
}

template <int TB>
__device__ __forceinline__ void ap_sx(float (&sx)[16], float (&sy)[16]) {
#pragma unroll
  for (int i = 0; i < 16; ++i) {
    if (i & TB) continue;
    const int j = i | TB;
    float ax = sx[i], ay = sy[i], bx = sx[j], by = sy[j];
    // a' = .5((1+i)a + (1-i)b) ; b' = .5((1-i)a + (1+i)b)
    sx[i] = 0.5f * (ax - ay + bx + by);  sy[i] = 0.5f * (ay + ax + by - bx);
    sx[j] = 0.5f * (ax + ay + bx - by);  sy[j] = 0.5f * (ay - ax + by + bx);
  }
}

template <int CB, int TB>
__device__ __forceinline__ void ap_cnot(float (&sx)[16], float (&sy)[16]) {
#pragma unroll
  for (int i = 0; i < 16; ++i) {
    if (!(i & CB) || (i & TB)) continue;
    const int j = i | TB;
    float tx = sx[i], ty = sy[i];
    sx[i] = sx[j]; sy[i] = sy[j];
    sx[j] = tx;    sy[j] = ty;
  }
}

template <int CB, int TB>
__device__ __forceinline__ void ap_crx(float (&sx)[16], float (&sy)[16],
                                       float c, float s) {
#pragma unroll
  for (int i = 0; i < 16; ++i) {
    if (!(i & CB) || (i & TB)) continue;
    const int j = i | TB;
    float ax = sx[i], ay = sy[i], bx = sx[j], by = sy[j];
    sx[i] = c * ax + s * by;  sy[i] = c * ay - s * bx;
    sx[j] = c * bx + s * ay;  sy[j] = c * by - s * ax;
  }
}

#define DISPATCH_1Q(FN, ...)                                   \
  switch (w0) {                                                \
    case 0: FN<8>(__VA_ARGS__); break;                         \
    case 1: FN<4>(__VA_ARGS__); break;                         \
    case 2: FN<2>(__VA_ARGS__); break;                         \
    default: FN<1>(__VA_ARGS__); break;                        \
  }

#define DISPATCH_2Q(FN, ...)                                   \
  switch (w0 * 4 + w1) {                                       \
    case 1:  FN<8, 4>(__VA_ARGS__); break;                     \
    case 2:  FN<8, 2>(__VA_ARGS__); break;                     \
    case 3:  FN<8, 1>(__VA_ARGS__); break;                     \
    case 4:  FN<4, 8>(__VA_ARGS__); break;                     \
    case 6:  FN<4, 2>(__VA_ARGS__); break;                     \
    case 7:  FN<4, 1>(__VA_ARGS__); break;                     \
    case 8:  FN<2, 8>(__VA_ARGS__); break;                     \
    case 9:  FN<2, 4>(__VA_ARGS__); break;                     \
    case 11: FN<2, 1>(__VA_ARGS__); break;                     \
    case 12: FN<1, 8>(__VA_ARGS__); break;                     \
    case 13: FN<1, 4>(__VA_ARGS__); break;                     \
    default: FN<1, 2>(__VA_ARGS__); break;                     \
  }

// ============================ Kernel A: build U_post ========================
__global__ __launch_bounds__(64) void build_u_kernel(
    GateList gl, const float* __restrict__ rand_params,
    const float* __restrict__ rx0, const float* __restrict__ ry0,
    const float* __restrict__ rz0, const float* __restrict__ crx0,
    float2* __restrict__ U_out) {
  __shared__ float theta_s[64];
  int t = threadIdx.x;
  if (t < gl.ng) {
    int pi = gl.pidx[t];
    float th = 0.f;
    if (pi >= 0)       th = rand_params[pi];
    else if (pi == -2) th = rx0[0];
    else if (pi == -3) th = ry0[0];
    else if (pi == -4) th = rz0[0];
    else if (pi == -5) th = crx0[0];
    theta_s[t] = th;
  }
  __syncthreads();

  int col = threadIdx.x;
  if (col >= 16) return;
  float sx[16], sy[16];
#pragma unroll
  for (int i = 0; i < 16; ++i) { sx[i] = (i == col) ? 1.f : 0.f; sy[i] = 0.f; }
  int ng = gl.ng;
  for (int g = 0; g < ng; ++g) {
    int kind = gl.kind[g], w0 = gl.w0[g], w1 = gl.w1[g];
    float th = theta_s[g];
    float c, s;
    __sincosf(0.5f * th, &s, &c);
    switch (kind) {
      case 0: DISPATCH_1Q(ap_rx, sx, sy, c, s); break;
      case 1: DISPATCH_1Q(ap_ry, sx, sy, c, s); break;
      case 2: DISPATCH_1Q(ap_rz, sx, sy, c, s); break;
      case 3: DISPATCH_2Q(ap_cnot, sx, sy); break;
      case 4: DISPATCH_2Q(ap_crx, sx, sy, c, s); break;
      case 5: DISPATCH_1Q(ap_h, sx, sy); break;
      default: DISPATCH_1Q(ap_sx, sx, sy); break;
    }
  }
#pragma unroll
  for (int i = 0; i < 16; ++i) U_out[i * 16 + col] = make_float2(sx[i], sy[i]);
}

// ===================== per-element ez (shared device fn) ====================
__device__ __forceinline__ void compute_ez(const float* __restrict__ features,
                                           long long b,
                                           const float2* __restrict__ Uld,
                                           float ez[4]) {
  const float4* fp = (const float4*)(features + b * 16);
  float4 F0 = fp[0], F1 = fp[1], F2 = fp[2], F3 = fp[3];
  float L0[4] = {F0.x, F0.y, F0.z, F0.w};
  float L1[4] = {F1.x, F1.y, F1.z, F1.w};
  float L2[4] = {F2.x, F2.y, F2.z, F2.w};
  float L3[4] = {F3.x, F3.y, F3.z, F3.w};
  float vax[4], vay[4], vbx[4], vby[4];
#pragma unroll
  for (int w = 0; w < 4; ++w) {
    // per-wire |0> column of RY(L3) RX(L2) RZ(L1) RY(L0)
    float s0, c0; __sincosf(0.5f * L0[w], &s0, &c0);
    float s1, c1; __sincosf(0.5f * L1[w], &s1, &c1);
    float s2, c2; __sincosf(0.5f * L2[w], &s2, &c2);
    float s3, c3; __sincosf(0.5f * L3[w], &s3, &c3);
    float ax = c0 * c1, ay = -c0 * s1;       // after RZ
    float bx = s0 * c1, by = s0 * s1;
    float a2x = c2 * ax + s2 * by, a2y = c2 * ay - s2 * bx;   // after RX
    float b2x = s2 * ay + c2 * bx, b2y = -s2 * ax + c2 * by;
    vax[w] = c3 * a2x - s3 * b2x; vay[w] = c3 * a2y - s3 * b2y;  // after RY
    vbx[w] = s3 * a2x + c3 * b2x; vby[w] = s3 * a2y + c3 * b2y;
  }
  // s = v0 (x) v1 (x) v2 (x) v3, wire0 = MSB
  float t01x[4], t01y[4], t23x[4], t23y[4];
  t01x[0] = vax[0] * vax[1] - vay[0] * vay[1]; t01y[0] = vax[0] * vay[1] + vay[0] * vax[1];
  t01x[1] = vax[0] * vbx[1] - vay[0] * vby[1]; t01y[1] = vax[0] * vby[1] + vay[0] * vbx[1];
  t01x[2] = vbx[0] * vax[1] - vby[0] * vay[1]; t01y[2] = vbx[0] * vay[1] + vby[0] * vax[1];
  t01x[3] = vbx[0] * vbx[1] - vby[0] * vby[1]; t01y[3] = vbx[0] * vby[1] + vby[0] * vbx[1];
  t23x[0] = vax[2] * vax[3] - vay[2] * vay[3]; t23y[0] = vax[2] * vay[3] + vay[2] * vax[3];
  t23x[1] = vax[2] * vbx[3] - vay[2] * vby[3]; t23y[1] = vax[2] * vby[3] + vay[2] * vbx[3];
  t23x[2] = vbx[2] * vax[3] - vby[2] * vay[3]; t23y[2] = vbx[2] * vay[3] + vby[2] * vax[3];
  t23x[3] = vbx[2] * vbx[3] - vby[2] * vby[3]; t23y[3] = vbx[2] * vby[3] + vby[2] * vbx[3];
  float sx[16], sy[16];
#pragma unroll
  for (int i = 0; i < 16; ++i) {
    int a = i >> 2, c = i & 3;
    sx[i] = t01x[a] * t23x[c] - t01y[a] * t23y[c];
    sy[i] = t01x[a] * t23y[c] + t01y[a] * t23x[c];
  }
  // s' = U_post s ; ez_w = sum_i sign(i,w) |s'_i|^2
  float e0 = 0.f, e1 = 0.f, e2 = 0.f, e3 = 0.f;
#pragma unroll
  for (int i = 0; i < 16; ++i) {
    float ax = 0.f, ay = 0.f;
#pragma unroll
    for (int j = 0; j < 16; ++j) {
      float2 u = Uld[i * 16 + j];
      ax += u.x * sx[j] - u.y * sy[j];
      ay += u.x * sy[j] + u.y * sx[j];
    }
    float p = ax * ax + ay * ay;
    e0 += (i & 8) ? -p : p;
    e1 += (i & 4) ? -p : p;
    e2 += (i & 2) ? -p : p;
    e3 += (i & 1) ? -p : p;
  }
  ez[0] = e0; ez[1] = e1; ez[2] = e2; ez[3] = e3;
}

// ===================== Kernel B: ez + block partial sums ====================
__global__ __launch_bounds__(256) void main_pass_kernel(
    const float* __restrict__ features, const float2* __restrict__ U,
    float* __restrict__ ez_out, float* __restrict__ partials, int B, int useEz) {
  __shared__ float2 ldsU[256];
  ldsU[threadIdx.x] = U[threadIdx.x];
  __syncthreads();

  long long b = (long long)blockIdx.x * 256 + threadIdx.x;
  float ez[4] = {0.f, 0.f, 0.f, 0.f};
  if (b < B) {
    compute_ez(features, b, ldsU, ez);
    if (useEz) ((float4*)ez_out)[b] = make_float4(ez[0], ez[1], ez[2], ez[3]);
  }
  float q[8] = {ez[0], ez[1], ez[2], ez[3],
                ez[0] * ez[0], ez[1] * ez[1], ez[2] * ez[2], ez[3] * ez[3]};
#pragma unroll
  for (int off = 32; off; off >>= 1)
#pragma unroll
    for (int k = 0; k < 8; ++k) q[k] += __shfl_down(q[k], off, 64);
  __shared__ float wred[4][8];
  int lane = threadIdx.x & 63, wv = threadIdx.x >> 6;
  if (lane == 0)
    for (int k = 0; k < 8; ++k) wred[wv][k] = q[k];
  __syncthreads();
  if (threadIdx.x == 0) {
    for (int k = 0; k < 8; ++k)
      partials[(size_t)blockIdx.x * 8 + k] =
          wred[0][k] + wred[1][k] + wred[2][k] + wred[3][k];
  }
}

// ================= Kernel C: reduce partials -> alpha, c0 ===================
__global__ __launch_bounds__(256) void stats_kernel(
    const float* __restrict__ partials, int nblk, const float* __restrict__ gamma,
    const float* __restrict__ beta, const float* __restrict__ W,
    const float* __restrict__ bias, float* __restrict__ coef, float invB) {
  float q[8] = {0.f, 0.f, 0.f, 0.f, 0.f, 0.f, 0.f, 0.f};
  for (int idx = threadIdx.x; idx < nblk; idx += 256)
    for (int k = 0; k < 8; ++k) q[k] += partials[(size_t)idx * 8 + k];
#pragma unroll
  for (int off = 32; off; off >>= 1)
#pragma unroll
    for (int k = 0; k < 8; ++k) q[k] += __shfl_down(q[k], off, 64);
  __shared__ float wred[4][8];
  int lane = threadIdx.x & 63, wv = threadIdx.x >> 6;
  if (lane == 0)
    for (int k = 0; k < 8; ++k) wred[wv][k] = q[k];
  __syncthreads();
  if (threadIdx.x == 0) {
    float c0 = bias[0];
    for (int w = 0; w < 4; ++w) {
      float Sw = wred[0][w] + wred[1][w] + wred[2][w] + wred[3][w];
      float Qw = wred[0][4 + w] + wred[1][4 + w] + wred[2][4 + w] + wred[3][4 + w];
      float mu = Sw * invB;
      float var = Qw * invB - mu * mu;
      float inv = rsqrtf(var + 1e-5f);
      coef[w] = W[w] * gamma[w] * inv;
      c0 += W[w] * (beta[w] - gamma[w] * mu * inv);
    }
    coef[4] = c0;
  }
}

// ======================= Kernel D: final output pass ========================
__global__ __launch_bounds__(256) void final_pass_kernel(
    const float* __restrict__ features, const float2* __restrict__ U,
    const float* __restrict__ ez_in, const float* __restrict__ coef,
    float* __restrict__ out, int B, int useEz) {
  __shared__ float2 ldsU[256];
  if (!useEz) {
    ldsU[threadIdx.x] = U[threadIdx.x];
    __syncthreads();
  }
  long long b = (long long)blockIdx.x * 256 + threadIdx.x;
  if (b >= B) return;
  float ez[4];
  if (useEz) {
    float4 e = ((const float4*)ez_in)[b];
    ez[0] = e.x; ez[1] = e.y; ez[2] = e.z; ez[3] = e.w;
  } else {
    compute_ez(features, b, ldsU, ez);
  }
  out[b] = coef[4] + coef[0] * ez[0] + coef[1] * ez[1] + coef[2] * ez[2] +
           coef[3] * ez[3];
}

// ================================ launch ====================================
extern "C" void kernel_launch(void* const* d_in, const int* in_sizes, int n_in,
                              void* d_out, int out_size, void* d_ws, size_t ws_size,
                              hipStream_t stream) {
  const float* features    = (const float*)d_in[0];
  const float* rand_params = (const float*)d_in[1];
  const float* rx0         = (const float*)d_in[2];
  const float* ry0         = (const float*)d_in[3];
  const float* rz0         = (const float*)d_in[4];
  const float* crx0        = (const float*)d_in[5];
  const float* gamma       = (const float*)d_in[6];
  const float* beta        = (const float*)d_in[7];
  const float* W           = (const float*)d_in[8];
  const float* bias        = (const float*)d_in[9];
  float* out = (float*)d_out;

  int B = in_sizes[0] / 16;
  int nblk = (B + 255) / 256;

  char* ws = (char*)d_ws;
  float2* U = (float2*)ws;                                   // 2048 B
  float* partials = (float*)(ws + 2048);                     // nblk*32 B
  float* coef = (float*)(ws + 2048 + (size_t)nblk * 32);     // 32 B
  size_t ez_off = (2048 + (size_t)nblk * 32 + 32 + 255) & ~(size_t)255;
  float* ez = (float*)(ws + ez_off);
  int useEz = (ws_size >= ez_off + (size_t)B * 16) ? 1 : 0;

  GateList gl = build_gate_list();  // host-side, deterministic each call

  build_u_kernel<<<1, 64, 0, stream>>>(gl, rand_params, rx0, ry0, rz0, crx0, U);
  main_pass_kernel<<<nblk, 256, 0, stream>>>(features, U, ez, partials, B, useEz);
  stats_kernel<<<1, 256, 0, stream>>>(partials, nblk, gamma, beta, W, bias, coef,
                                      1.0f / (float)B);
  final_pass_kernel<<<nblk, 256, 0, stream>>>(features, U, ez, coef, out, B, useEz);
}

// Round 4
// 26.974 us; speedup vs baseline: 7.9848x; 1.6989x over previous
//
#include <hip/hip_runtime.h>
#include <math.h>

// ---------------------------------------------------------------------------
// FraudDetectionHybrid: 4-qubit statevector sim, algebraically collapsed.
//   encoder -> product state (per-wire 2-vectors)           [device, per-elem]
//   RandomLayer + trainable block -> fixed 16x16 unitary U_post, built by a
//     1-wave kernel whose gate sequence is a COMPILE-TIME constant
//     (constexpr MT19937, seed 42 -> template-unrolled straight-line code)
//   measure <Z_w> -> sign-sums of |U_post s|^2
//   BatchNorm(batch stats) + Linear -> out[b] = sum_w a_w ez[b,w] + c0
//
// R1 lesson: MT19937 on device -> scratch serial chain (240us).
// R2 lesson: runtime-indexed sx[16]/sy[16] -> scratch (100us).
// R3 lesson: runtime-indexed GateList kernel-arg arrays -> scratch AGAIN.
//   Now the whole gate sequence is constexpr; no runtime indexing survives.
// ---------------------------------------------------------------------------

// ==================== compile-time numpy RandomState(42) ====================
struct CGates {
  int kind[64];   // 0=RX 1=RY 2=RZ 3=CNOT 4=CRX 5=H 6=SX
  int w0[64];
  int w1[64];
  int pidx[64];   // >=0: rand_params idx; -1 none; -2 rx0; -3 ry0; -4 rz0; -5 crx0
  int ng;
};

constexpr unsigned int c_mt_next(unsigned int (&mt)[624], int& pos) {
  if (pos >= 624) {
    for (int i = 0; i < 624; ++i) {
      unsigned int y = (mt[i] & 0x80000000u) | (mt[(i + 1) % 624] & 0x7fffffffu);
      unsigned int v = mt[(i + 397) % 624] ^ (y >> 1);
      if (y & 1u) v ^= 0x9908b0dfu;
      mt[i] = v;
    }
    pos = 0;
  }
  unsigned int y = mt[pos++];
  y ^= y >> 11;
  y ^= (y << 7) & 0x9d2c5680u;
  y ^= (y << 15) & 0xefc60000u;
  y ^= y >> 18;
  return y;
}

constexpr CGates make_gates() {
  CGates gl{};
  unsigned int mt[624] = {};
  mt[0] = 42u;
  for (int i = 1; i < 624; ++i)
    mt[i] = 1812433253u * (mt[i - 1] ^ (mt[i - 1] >> 30)) + (unsigned int)i;
  int pos = 624;
  int ng = 0, p = 0;
  for (int op = 0; op < 50; ++op) {
    unsigned int k = c_mt_next(mt, pos) & 3u;   // randint(4): one draw, mask 3
    if (k < 3u) {
      unsigned int w = c_mt_next(mt, pos) & 3u; // wire
      gl.kind[ng] = (int)k; gl.w0[ng] = (int)w; gl.w1[ng] = 0;
      gl.pidx[ng] = p++;
      ++ng;
    } else {
      // choice(4,2,replace=False): Fisher-Yates descending, mask-rejection
      int arr[4] = {0, 1, 2, 3};
      { unsigned int j = c_mt_next(mt, pos) & 3u;
        int t = arr[3]; arr[3] = arr[j]; arr[j] = t; }
      { unsigned int j = c_mt_next(mt, pos) & 3u;
        while (j > 2u) j = c_mt_next(mt, pos) & 3u;
        int t = arr[2]; arr[2] = arr[j]; arr[j] = t; }
      { unsigned int j = c_mt_next(mt, pos) & 1u;
        int t = arr[1]; arr[1] = arr[j]; arr[j] = t; }
      gl.kind[ng] = 3; gl.w0[ng] = arr[0]; gl.w1[ng] = arr[1]; gl.pidx[ng] = -1;
      ++ng;
    }
  }
  // trainable block
  gl.kind[ng] = 0; gl.w0[ng] = 0; gl.w1[ng] = 0; gl.pidx[ng] = -2; ++ng; // RX w0
  gl.kind[ng] = 1; gl.w0[ng] = 1; gl.w1[ng] = 0; gl.pidx[ng] = -3; ++ng; // RY w1
  gl.kind[ng] = 2; gl.w0[ng] = 3; gl.w1[ng] = 0; gl.pidx[ng] = -4; ++ng; // RZ w3
  gl.kind[ng] = 4; gl.w0[ng] = 0; gl.w1[ng] = 2; gl.pidx[ng] = -5; ++ng; // CRX(0,2)
  gl.kind[ng] = 5; gl.w0[ng] = 3; gl.w1[ng] = 0; gl.pidx[ng] = -1; ++ng; // H w3
  gl.kind[ng] = 6; gl.w0[ng] = 2; gl.w1[ng] = 0; gl.pidx[ng] = -1; ++ng; // SX w2
  gl.kind[ng] = 3; gl.w0[ng] = 3; gl.w1[ng] = 0; gl.pidx[ng] = -1; ++ng; // CNOT(3,0)
  gl.ng = ng;
  return gl;
}

inline constexpr CGates GL = make_gates();

// ================= templated gate appliers (static indices) =================
// wire0 = MSB (bit 3): TB = 8 >> wire.

template <int TB>
__device__ __forceinline__ void ap_rx(float (&sx)[16], float (&sy)[16],
                                      float c, float s) {
#pragma unroll
  for (int i = 0; i < 16; ++i) {
    if (i & TB) continue;
    const int j = i | TB;
    float ax = sx[i], ay = sy[i], bx = sx[j], by = sy[j];
    sx[i] = c * ax + s * by;  sy[i] = c * ay - s * bx;   // a' = c a - i s b
    sx[j] = c * bx + s * ay;  sy[j] = c * by - s * ax;   // b' = -i s a + c b
  }
}

template <int TB>
__device__ __forceinline__ void ap_ry(float (&sx)[16], float (&sy)[16],
                                      float c, float s) {
#pragma unroll
  for (int i = 0; i < 16; ++i) {
    if (i & TB) continue;
    const int j = i | TB;
    float ax = sx[i], ay = sy[i], bx = sx[j], by = sy[j];
    sx[i] = c * ax - s * bx;  sy[i] = c * ay - s * by;   // a' = c a - s b
    sx[j] = s * ax + c * bx;  sy[j] = s * ay + c * by;   // b' = s a + c b
  }
}

template <int TB>
__device__ __forceinline__ void ap_rz(float (&sx)[16], float (&sy)[16],
                                      float c, float s) {
#pragma unroll
  for (int i = 0; i < 16; ++i) {
    if (i & TB) continue;
    const int j = i | TB;
    float ax = sx[i], ay = sy[i], bx = sx[j], by = sy[j];
    sx[i] = c * ax + s * ay;  sy[i] = c * ay - s * ax;   // a' = (c - i s) a
    sx[j] = c * bx - s * by;  sy[j] = c * by + s * bx;   // b' = (c + i s) b
  }
}

template <int TB>
__device__ __forceinline__ void ap_h(float (&sx)[16], float (&sy)[16]) {
  const float r = 0.70710678118654752f;
#pragma unroll
  for (int i = 0; i < 16; ++i) {
    if (i & TB) continue;
    const int j = i | TB;
    float ax = sx[i], ay = sy[i], bx = sx[j], by = sy[j];
    sx[i] = r * (ax + bx);  sy[i] = r * (ay + by);
    sx[j] = r * (ax - bx);  sy[j] = r * (ay - by);
  }
}

template <int TB>
__device__ __forceinline__ void ap_sxg(float (&sx)[16], float (&sy)[16]) {
#pragma unroll
  for (int i = 0; i < 16; ++i) {
    if (i & TB) continue;
    const int j = i | TB;
    float ax = sx[i], ay = sy[i], bx = sx[j], by = sy[j];
    // a' = .5((1+i)a + (1-i)b) ; b' = .5((1-i)a + (1+i)b)
    sx[i] = 0.5f * (ax - ay + bx + by);  sy[i] = 0.5f * (ay + ax + by - bx);
    sx[j] = 0.5f * (ax + ay + bx - by);  sy[j] = 0.5f * (ay - ax + by + bx);
  }
}

template <int CB, int TB>
__device__ __forceinline__ void ap_cnot(float (&sx)[16], float (&sy)[16]) {
#pragma unroll
  for (int i = 0; i < 16; ++i) {
    if (!(i & CB) || (i & TB)) continue;
    const int j = i | TB;
    float tx = sx[i], ty = sy[i];
    sx[i] = sx[j]; sy[i] = sy[j];
    sx[j] = tx;    sy[j] = ty;
  }
}

template <int CB, int TB>
__device__ __forceinline__ void ap_crx(float (&sx)[16], float (&sy)[16],
                                       float c, float s) {
#pragma unroll
  for (int i = 0; i < 16; ++i) {
    if (!(i & CB) || (i & TB)) continue;
    const int j = i | TB;
    float ax = sx[i], ay = sy[i], bx = sx[j], by = sy[j];
    sx[i] = c * ax + s * by;  sy[i] = c * ay - s * bx;
    sx[j] = c * bx + s * ay;  sy[j] = c * by - s * ax;
  }
}

// ================= compile-time-unrolled gate chain =========================
template <int G>
__device__ __forceinline__ void apply_gates(
    float (&sx)[16], float (&sy)[16], const float* __restrict__ rp,
    const float* __restrict__ rx0, const float* __restrict__ ry0,
    const float* __restrict__ rz0, const float* __restrict__ crx0) {
  if constexpr (G < GL.ng) {
    constexpr int kind = GL.kind[G];
    constexpr int TB0 = 8 >> GL.w0[G];
    constexpr int TB1 = 8 >> GL.w1[G];
    constexpr int pi = GL.pidx[G];
    float c = 0.f, s = 0.f;
    if constexpr (kind == 0 || kind == 1 || kind == 2 || kind == 4) {
      float th;
      if constexpr (pi >= 0)       th = rp[pi];
      else if constexpr (pi == -2) th = rx0[0];
      else if constexpr (pi == -3) th = ry0[0];
      else if constexpr (pi == -4) th = rz0[0];
      else                         th = crx0[0];
      __sincosf(0.5f * th, &s, &c);
    }
    if constexpr (kind == 0)      ap_rx<TB0>(sx, sy, c, s);
    else if constexpr (kind == 1) ap_ry<TB0>(sx, sy, c, s);
    else if constexpr (kind == 2) ap_rz<TB0>(sx, sy, c, s);
    else if constexpr (kind == 3) ap_cnot<TB0, TB1>(sx, sy);
    else if constexpr (kind == 4) ap_crx<TB0, TB1>(sx, sy, c, s);
    else if constexpr (kind == 5) ap_h<TB0>(sx, sy);
    else                          ap_sxg<TB0>(sx, sy);
    apply_gates<G + 1>(sx, sy, rp, rx0, ry0, rz0, crx0);
  }
}

// ============================ Kernel A: build U_post ========================
__global__ __launch_bounds__(64) void build_u_kernel(
    const float* __restrict__ rand_params, const float* __restrict__ rx0,
    const float* __restrict__ ry0, const float* __restrict__ rz0,
    const float* __restrict__ crx0, float2* __restrict__ U_out) {
  int col = threadIdx.x;
  if (col >= 16) return;
  float sx[16], sy[16];
#pragma unroll
  for (int i = 0; i < 16; ++i) { sx[i] = (i == col) ? 1.f : 0.f; sy[i] = 0.f; }
  apply_gates<0>(sx, sy, rand_params, rx0, ry0, rz0, crx0);
#pragma unroll
  for (int i = 0; i < 16; ++i) U_out[i * 16 + col] = make_float2(sx[i], sy[i]);
}

// ===================== per-element ez (shared device fn) ====================
__device__ __forceinline__ void compute_ez(const float* __restrict__ features,
                                           long long b,
                                           const float2* __restrict__ Uld,
                                           float ez[4]) {
  const float4* fp = (const float4*)(features + b * 16);
  float4 F0 = fp[0], F1 = fp[1], F2 = fp[2], F3 = fp[3];
  float L0[4] = {F0.x, F0.y, F0.z, F0.w};
  float L1[4] = {F1.x, F1.y, F1.z, F1.w};
  float L2[4] = {F2.x, F2.y, F2.z, F2.w};
  float L3[4] = {F3.x, F3.y, F3.z, F3.w};
  float vax[4], vay[4], vbx[4], vby[4];
#pragma unroll
  for (int w = 0; w < 4; ++w) {
    // per-wire |0> column of RY(L3) RX(L2) RZ(L1) RY(L0)
    float s0, c0; __sincosf(0.5f * L0[w], &s0, &c0);
    float s1, c1; __sincosf(0.5f * L1[w], &s1, &c1);
    float s2, c2; __sincosf(0.5f * L2[w], &s2, &c2);
    float s3, c3; __sincosf(0.5f * L3[w], &s3, &c3);
    float ax = c0 * c1, ay = -c0 * s1;       // after RZ
    float bx = s0 * c1, by = s0 * s1;
    float a2x = c2 * ax + s2 * by, a2y = c2 * ay - s2 * bx;   // after RX
    float b2x = s2 * ay + c2 * bx, b2y = -s2 * ax + c2 * by;
    vax[w] = c3 * a2x - s3 * b2x; vay[w] = c3 * a2y - s3 * b2y;  // after RY
    vbx[w] = s3 * a2x + c3 * b2x; vby[w] = s3 * a2y + c3 * b2y;
  }
  // s = v0 (x) v1 (x) v2 (x) v3, wire0 = MSB
  float t01x[4], t01y[4], t23x[4], t23y[4];
  t01x[0] = vax[0] * vax[1] - vay[0] * vay[1]; t01y[0] = vax[0] * vay[1] + vay[0] * vax[1];
  t01x[1] = vax[0] * vbx[1] - vay[0] * vby[1]; t01y[1] = vax[0] * vby[1] + vay[0] * vbx[1];
  t01x[2] = vbx[0] * vax[1] - vby[0] * vay[1]; t01y[2] = vbx[0] * vay[1] + vby[0] * vax[1];
  t01x[3] = vbx[0] * vbx[1] - vby[0] * vby[1]; t01y[3] = vbx[0] * vby[1] + vby[0] * vbx[1];
  t23x[0] = vax[2] * vax[3] - vay[2] * vay[3]; t23y[0] = vax[2] * vay[3] + vay[2] * vax[3];
  t23x[1] = vax[2] * vbx[3] - vay[2] * vby[3]; t23y[1] = vax[2] * vby[3] + vay[2] * vbx[3];
  t23x[2] = vbx[2] * vax[3] - vby[2] * vay[3]; t23y[2] = vbx[2] * vay[3] + vby[2] * vax[3];
  t23x[3] = vbx[2] * vbx[3] - vby[2] * vby[3]; t23y[3] = vbx[2] * vby[3] + vby[2] * vbx[3];
  float sx[16], sy[16];
#pragma unroll
  for (int i = 0; i < 16; ++i) {
    int a = i >> 2, c = i & 3;
    sx[i] = t01x[a] * t23x[c] - t01y[a] * t23y[c];
    sy[i] = t01x[a] * t23y[c] + t01y[a] * t23x[c];
  }
  // s' = U_post s ; ez_w = sum_i sign(i,w) |s'_i|^2
  float e0 = 0.f, e1 = 0.f, e2 = 0.f, e3 = 0.f;
#pragma unroll
  for (int i = 0; i < 16; ++i) {
    float ax = 0.f, ay = 0.f;
#pragma unroll
    for (int j = 0; j < 16; ++j) {
      float2 u = Uld[i * 16 + j];
      ax += u.x * sx[j] - u.y * sy[j];
      ay += u.x * sy[j] + u.y * sx[j];
    }
    float p = ax * ax + ay * ay;
    e0 += (i & 8) ? -p : p;
    e1 += (i & 4) ? -p : p;
    e2 += (i & 2) ? -p : p;
    e3 += (i & 1) ? -p : p;
  }
  ez[0] = e0; ez[1] = e1; ez[2] = e2; ez[3] = e3;
}

// ===================== Kernel B: ez + block partial sums ====================
__global__ __launch_bounds__(256) void main_pass_kernel(
    const float* __restrict__ features, const float2* __restrict__ U,
    float* __restrict__ ez_out, float* __restrict__ partials, int B, int useEz) {
  __shared__ float2 ldsU[256];
  ldsU[threadIdx.x] = U[threadIdx.x];
  __syncthreads();

  long long b = (long long)blockIdx.x * 256 + threadIdx.x;
  float ez[4] = {0.f, 0.f, 0.f, 0.f};
  if (b < B) {
    compute_ez(features, b, ldsU, ez);
    if (useEz) ((float4*)ez_out)[b] = make_float4(ez[0], ez[1], ez[2], ez[3]);
  }
  float q[8] = {ez[0], ez[1], ez[2], ez[3],
                ez[0] * ez[0], ez[1] * ez[1], ez[2] * ez[2], ez[3] * ez[3]};
#pragma unroll
  for (int off = 32; off; off >>= 1)
#pragma unroll
    for (int k = 0; k < 8; ++k) q[k] += __shfl_down(q[k], off, 64);
  __shared__ float wred[4][8];
  int lane = threadIdx.x & 63, wv = threadIdx.x >> 6;
  if (lane == 0)
    for (int k = 0; k < 8; ++k) wred[wv][k] = q[k];
  __syncthreads();
  if (threadIdx.x == 0) {
    for (int k = 0; k < 8; ++k)
      partials[(size_t)blockIdx.x * 8 + k] =
          wred[0][k] + wred[1][k] + wred[2][k] + wred[3][k];
  }
}

// ================= Kernel C: reduce partials -> alpha, c0 ===================
__global__ __launch_bounds__(256) void stats_kernel(
    const float* __restrict__ partials, int nblk, const float* __restrict__ gamma,
    const float* __restrict__ beta, const float* __restrict__ W,
    const float* __restrict__ bias, float* __restrict__ coef, float invB) {
  float q[8] = {0.f, 0.f, 0.f, 0.f, 0.f, 0.f, 0.f, 0.f};
  for (int idx = threadIdx.x; idx < nblk; idx += 256)
    for (int k = 0; k < 8; ++k) q[k] += partials[(size_t)idx * 8 + k];
#pragma unroll
  for (int off = 32; off; off >>= 1)
#pragma unroll
    for (int k = 0; k < 8; ++k) q[k] += __shfl_down(q[k], off, 64);
  __shared__ float wred[4][8];
  int lane = threadIdx.x & 63, wv = threadIdx.x >> 6;
  if (lane == 0)
    for (int k = 0; k < 8; ++k) wred[wv][k] = q[k];
  __syncthreads();
  if (threadIdx.x == 0) {
    float c0 = bias[0];
    for (int w = 0; w < 4; ++w) {
      float Sw = wred[0][w] + wred[1][w] + wred[2][w] + wred[3][w];
      float Qw = wred[0][4 + w] + wred[1][4 + w] + wred[2][4 + w] + wred[3][4 + w];
      float mu = Sw * invB;
      float var = Qw * invB - mu * mu;
      float inv = rsqrtf(var + 1e-5f);
      coef[w] = W[w] * gamma[w] * inv;
      c0 += W[w] * (beta[w] - gamma[w] * mu * inv);
    }
    coef[4] = c0;
  }
}

// ======================= Kernel D: final output pass ========================
__global__ __launch_bounds__(256) void final_pass_kernel(
    const float* __restrict__ features, const float2* __restrict__ U,
    const float* __restrict__ ez_in, const float* __restrict__ coef,
    float* __restrict__ out, int B, int useEz) {
  __shared__ float2 ldsU[256];
  if (!useEz) {
    ldsU[threadIdx.x] = U[threadIdx.x];
    __syncthreads();
  }
  long long b = (long long)blockIdx.x * 256 + threadIdx.x;
  if (b >= B) return;
  float ez[4];
  if (useEz) {
    float4 e = ((const float4*)ez_in)[b];
    ez[0] = e.x; ez[1] = e.y; ez[2] = e.z; ez[3] = e.w;
  } else {
    compute_ez(features, b, ldsU, ez);
  }
  out[b] = coef[4] + coef[0] * ez[0] + coef[1] * ez[1] + coef[2] * ez[2] +
           coef[3] * ez[3];
}

// ================================ launch ====================================
extern "C" void kernel_launch(void* const* d_in, const int* in_sizes, int n_in,
                              void* d_out, int out_size, void* d_ws, size_t ws_size,
                              hipStream_t stream) {
  const float* features    = (const float*)d_in[0];
  const float* rand_params = (const float*)d_in[1];
  const float* rx0         = (const float*)d_in[2];
  const float* ry0         = (const float*)d_in[3];
  const float* rz0         = (const float*)d_in[4];
  const float* crx0        = (const float*)d_in[5];
  const float* gamma       = (const float*)d_in[6];
  const float* beta        = (const float*)d_in[7];
  const float* W           = (const float*)d_in[8];
  const float* bias        = (const float*)d_in[9];
  float* out = (float*)d_out;

  int B = in_sizes[0] / 16;
  int nblk = (B + 255) / 256;

  char* ws = (char*)d_ws;
  float2* U = (float2*)ws;                                   // 2048 B
  float* partials = (float*)(ws + 2048);                     // nblk*32 B
  float* coef = (float*)(ws + 2048 + (size_t)nblk * 32);     // 32 B
  size_t ez_off = (2048 + (size_t)nblk * 32 + 32 + 255) & ~(size_t)255;
  float* ez = (float*)(ws + ez_off);
  int useEz = (ws_size >= ez_off + (size_t)B * 16) ? 1 : 0;

  build_u_kernel<<<1, 64, 0, stream>>>(rand_params, rx0, ry0, rz0, crx0, U);
  main_pass_kernel<<<nblk, 256, 0, stream>>>(features, U, ez, partials, B, useEz);
  stats_kernel<<<1, 256, 0, stream>>>(partials, nblk, gamma, beta, W, bias, coef,
                                      1.0f / (float)B);
  final_pass_kernel<<<nblk, 256, 0, stream>>>(features, U, ez, coef, out, B, useEz);
}

// Round 5
// 25.873 us; speedup vs baseline: 8.3247x; 1.0426x over previous
//
#include <hip/hip_runtime.h>
#include <math.h>

// ---------------------------------------------------------------------------
// FraudDetectionHybrid: 4-qubit statevector sim, algebraically collapsed.
//   encoder -> product state (per-wire 2-vectors)           [device, per-elem]
//   RandomLayer + trainable block -> fixed 16x16 unitary U_post, built
//     per-block by wave-0 lanes 0..15 from a COMPILE-TIME gate sequence
//     (constexpr MT19937 seed 42 -> template-unrolled straight-line code)
//   measure <Z_w> -> sign-sums of |U_post s|^2
//   BatchNorm(batch stats) + Linear -> out[b] = sum_w a_w ez[b,w] + c0
//
// R1 lesson: MT19937 on device -> scratch serial chain (240us).
// R2 lesson: runtime-indexed sx[16]/sy[16] -> scratch (100us).
// R3 lesson: runtime-indexed GateList kernel-arg arrays -> scratch again.
// R4 lesson: work is ~7us; 4 serial graph dispatches cost ~20us -> fuse to 2:
//   K1 = U-build (per-block, redundant) + encoder + matvec + partial sums
//   K2 = redundant per-block stats reduce -> coef -> output pass
// ---------------------------------------------------------------------------

// ==================== compile-time numpy RandomState(42) ====================
struct CGates {
  int kind[64];   // 0=RX 1=RY 2=RZ 3=CNOT 4=CRX 5=H 6=SX
  int w0[64];
  int w1[64];
  int pidx[64];   // >=0: rand_params idx; -1 none; -2 rx0; -3 ry0; -4 rz0; -5 crx0
  int ng;
};

constexpr unsigned int c_mt_next(unsigned int (&mt)[624], int& pos) {
  if (pos >= 624) {
    for (int i = 0; i < 624; ++i) {
      unsigned int y = (mt[i] & 0x80000000u) | (mt[(i + 1) % 624] & 0x7fffffffu);
      unsigned int v = mt[(i + 397) % 624] ^ (y >> 1);
      if (y & 1u) v ^= 0x9908b0dfu;
      mt[i] = v;
    }
    pos = 0;
  }
  unsigned int y = mt[pos++];
  y ^= y >> 11;
  y ^= (y << 7) & 0x9d2c5680u;
  y ^= (y << 15) & 0xefc60000u;
  y ^= y >> 18;
  return y;
}

constexpr CGates make_gates() {
  CGates gl{};
  unsigned int mt[624] = {};
  mt[0] = 42u;
  for (int i = 1; i < 624; ++i)
    mt[i] = 1812433253u * (mt[i - 1] ^ (mt[i - 1] >> 30)) + (unsigned int)i;
  int pos = 624;
  int ng = 0, p = 0;
  for (int op = 0; op < 50; ++op) {
    unsigned int k = c_mt_next(mt, pos) & 3u;   // randint(4): one draw, mask 3
    if (k < 3u) {
      unsigned int w = c_mt_next(mt, pos) & 3u; // wire
      gl.kind[ng] = (int)k; gl.w0[ng] = (int)w; gl.w1[ng] = 0;
      gl.pidx[ng] = p++;
      ++ng;
    } else {
      // choice(4,2,replace=False): Fisher-Yates descending, mask-rejection
      int arr[4] = {0, 1, 2, 3};
      { unsigned int j = c_mt_next(mt, pos) & 3u;
        int t = arr[3]; arr[3] = arr[j]; arr[j] = t; }
      { unsigned int j = c_mt_next(mt, pos) & 3u;
        while (j > 2u) j = c_mt_next(mt, pos) & 3u;
        int t = arr[2]; arr[2] = arr[j]; arr[j] = t; }
      { unsigned int j = c_mt_next(mt, pos) & 1u;
        int t = arr[1]; arr[1] = arr[j]; arr[j] = t; }
      gl.kind[ng] = 3; gl.w0[ng] = arr[0]; gl.w1[ng] = arr[1]; gl.pidx[ng] = -1;
      ++ng;
    }
  }
  // trainable block
  gl.kind[ng] = 0; gl.w0[ng] = 0; gl.w1[ng] = 0; gl.pidx[ng] = -2; ++ng; // RX w0
  gl.kind[ng] = 1; gl.w0[ng] = 1; gl.w1[ng] = 0; gl.pidx[ng] = -3; ++ng; // RY w1
  gl.kind[ng] = 2; gl.w0[ng] = 3; gl.w1[ng] = 0; gl.pidx[ng] = -4; ++ng; // RZ w3
  gl.kind[ng] = 4; gl.w0[ng] = 0; gl.w1[ng] = 2; gl.pidx[ng] = -5; ++ng; // CRX(0,2)
  gl.kind[ng] = 5; gl.w0[ng] = 3; gl.w1[ng] = 0; gl.pidx[ng] = -1; ++ng; // H w3
  gl.kind[ng] = 6; gl.w0[ng] = 2; gl.w1[ng] = 0; gl.pidx[ng] = -1; ++ng; // SX w2
  gl.kind[ng] = 3; gl.w0[ng] = 3; gl.w1[ng] = 0; gl.pidx[ng] = -1; ++ng; // CNOT(3,0)
  gl.ng = ng;
  return gl;
}

inline constexpr CGates GL = make_gates();

// ================= templated gate appliers (static indices) =================
// wire0 = MSB (bit 3): TB = 8 >> wire.

template <int TB>
__device__ __forceinline__ void ap_rx(float (&sx)[16], float (&sy)[16],
                                      float c, float s) {
#pragma unroll
  for (int i = 0; i < 16; ++i) {
    if (i & TB) continue;
    const int j = i | TB;
    float ax = sx[i], ay = sy[i], bx = sx[j], by = sy[j];
    sx[i] = c * ax + s * by;  sy[i] = c * ay - s * bx;   // a' = c a - i s b
    sx[j] = c * bx + s * ay;  sy[j] = c * by - s * ax;   // b' = -i s a + c b
  }
}

template <int TB>
__device__ __forceinline__ void ap_ry(float (&sx)[16], float (&sy)[16],
                                      float c, float s) {
#pragma unroll
  for (int i = 0; i < 16; ++i) {
    if (i & TB) continue;
    const int j = i | TB;
    float ax = sx[i], ay = sy[i], bx = sx[j], by = sy[j];
    sx[i] = c * ax - s * bx;  sy[i] = c * ay - s * by;   // a' = c a - s b
    sx[j] = s * ax + c * bx;  sy[j] = s * ay + c * by;   // b' = s a + c b
  }
}

template <int TB>
__device__ __forceinline__ void ap_rz(float (&sx)[16], float (&sy)[16],
                                      float c, float s) {
#pragma unroll
  for (int i = 0; i < 16; ++i) {
    if (i & TB) continue;
    const int j = i | TB;
    float ax = sx[i], ay = sy[i], bx = sx[j], by = sy[j];
    sx[i] = c * ax + s * ay;  sy[i] = c * ay - s * ax;   // a' = (c - i s) a
    sx[j] = c * bx - s * by;  sy[j] = c * by + s * bx;   // b' = (c + i s) b
  }
}

template <int TB>
__device__ __forceinline__ void ap_h(float (&sx)[16], float (&sy)[16]) {
  const float r = 0.70710678118654752f;
#pragma unroll
  for (int i = 0; i < 16; ++i) {
    if (i & TB) continue;
    const int j = i | TB;
    float ax = sx[i], ay = sy[i], bx = sx[j], by = sy[j];
    sx[i] = r * (ax + bx);  sy[i] = r * (ay + by);
    sx[j] = r * (ax - bx);  sy[j] = r * (ay - by);
  }
}

template <int TB>
__device__ __forceinline__ void ap_sxg(float (&sx)[16], float (&sy)[16]) {
#pragma unroll
  for (int i = 0; i < 16; ++i) {
    if (i & TB) continue;
    const int j = i | TB;
    float ax = sx[i], ay = sy[i], bx = sx[j], by = sy[j];
    // a' = .5((1+i)a + (1-i)b) ; b' = .5((1-i)a + (1+i)b)
    sx[i] = 0.5f * (ax - ay + bx + by);  sy[i] = 0.5f * (ay + ax + by - bx);
    sx[j] = 0.5f * (ax + ay + bx - by);  sy[j] = 0.5f * (ay - ax + by + bx);
  }
}

template <int CB, int TB>
__device__ __forceinline__ void ap_cnot(float (&sx)[16], float (&sy)[16]) {
#pragma unroll
  for (int i = 0; i < 16; ++i) {
    if (!(i & CB) || (i & TB)) continue;
    const int j = i | TB;
    float tx = sx[i], ty = sy[i];
    sx[i] = sx[j]; sy[i] = sy[j];
    sx[j] = tx;    sy[j] = ty;
  }
}

template <int CB, int TB>
__device__ __forceinline__ void ap_crx(float (&sx)[16], float (&sy)[16],
                                       float c, float s) {
#pragma unroll
  for (int i = 0; i < 16; ++i) {
    if (!(i & CB) || (i & TB)) continue;
    const int j = i | TB;
    float ax = sx[i], ay = sy[i], bx = sx[j], by = sy[j];
    sx[i] = c * ax + s * by;  sy[i] = c * ay - s * bx;
    sx[j] = c * bx + s * ay;  sy[j] = c * by - s * ax;
  }
}

// ================= compile-time-unrolled gate chain =========================
template <int G>
__device__ __forceinline__ void apply_gates(
    float (&sx)[16], float (&sy)[16], const float* __restrict__ rp,
    const float* __restrict__ rx0, const float* __restrict__ ry0,
    const float* __restrict__ rz0, const float* __restrict__ crx0) {
  if constexpr (G < GL.ng) {
    constexpr int kind = GL.kind[G];
    constexpr int TB0 = 8 >> GL.w0[G];
    constexpr int TB1 = 8 >> GL.w1[G];
    constexpr int pi = GL.pidx[G];
    float c = 0.f, s = 0.f;
    if constexpr (kind == 0 || kind == 1 || kind == 2 || kind == 4) {
      float th;
      if constexpr (pi >= 0)       th = rp[pi];
      else if constexpr (pi == -2) th = rx0[0];
      else if constexpr (pi == -3) th = ry0[0];
      else if constexpr (pi == -4) th = rz0[0];
      else                         th = crx0[0];
      __sincosf(0.5f * th, &s, &c);
    }
    if constexpr (kind == 0)      ap_rx<TB0>(sx, sy, c, s);
    else if constexpr (kind == 1) ap_ry<TB0>(sx, sy, c, s);
    else if constexpr (kind == 2) ap_rz<TB0>(sx, sy, c, s);
    else if constexpr (kind == 3) ap_cnot<TB0, TB1>(sx, sy);
    else if constexpr (kind == 4) ap_crx<TB0, TB1>(sx, sy, c, s);
    else if constexpr (kind == 5) ap_h<TB0>(sx, sy);
    else                          ap_sxg<TB0>(sx, sy);
    apply_gates<G + 1>(sx, sy, rp, rx0, ry0, rz0, crx0);
  }
}

// ===================== per-element ez, split in two phases ==================
// phase 1: encoder product state (no U needed)
__device__ __forceinline__ void phase1(const float* __restrict__ features,
                                       long long b, float (&t01x)[4],
                                       float (&t01y)[4], float (&t23x)[4],
                                       float (&t23y)[4]) {
  const float4* fp = (const float4*)(features + b * 16);
  float4 F0 = fp[0], F1 = fp[1], F2 = fp[2], F3 = fp[3];
  float L0[4] = {F0.x, F0.y, F0.z, F0.w};
  float L1[4] = {F1.x, F1.y, F1.z, F1.w};
  float L2[4] = {F2.x, F2.y, F2.z, F2.w};
  float L3[4] = {F3.x, F3.y, F3.z, F3.w};
  float vax[4], vay[4], vbx[4], vby[4];
#pragma unroll
  for (int w = 0; w < 4; ++w) {
    // per-wire |0> column of RY(L3) RX(L2) RZ(L1) RY(L0)
    float s0, c0; __sincosf(0.5f * L0[w], &s0, &c0);
    float s1, c1; __sincosf(0.5f * L1[w], &s1, &c1);
    float s2, c2; __sincosf(0.5f * L2[w], &s2, &c2);
    float s3, c3; __sincosf(0.5f * L3[w], &s3, &c3);
    float ax = c0 * c1, ay = -c0 * s1;       // after RZ
    float bx = s0 * c1, by = s0 * s1;
    float a2x = c2 * ax + s2 * by, a2y = c2 * ay - s2 * bx;   // after RX
    float b2x = s2 * ay + c2 * bx, b2y = -s2 * ax + c2 * by;
    vax[w] = c3 * a2x - s3 * b2x; vay[w] = c3 * a2y - s3 * b2y;  // after RY
    vbx[w] = s3 * a2x + c3 * b2x; vby[w] = s3 * a2y + c3 * b2y;
  }
  // pairwise tensor products (wire0 = MSB)
  t01x[0] = vax[0] * vax[1] - vay[0] * vay[1]; t01y[0] = vax[0] * vay[1] + vay[0] * vax[1];
  t01x[1] = vax[0] * vbx[1] - vay[0] * vby[1]; t01y[1] = vax[0] * vby[1] + vay[0] * vbx[1];
  t01x[2] = vbx[0] * vax[1] - vby[0] * vay[1]; t01y[2] = vbx[0] * vay[1] + vby[0] * vax[1];
  t01x[3] = vbx[0] * vbx[1] - vby[0] * vby[1]; t01y[3] = vbx[0] * vby[1] + vby[0] * vbx[1];
  t23x[0] = vax[2] * vax[3] - vay[2] * vay[3]; t23y[0] = vax[2] * vay[3] + vay[2] * vax[3];
  t23x[1] = vax[2] * vbx[3] - vay[2] * vby[3]; t23y[1] = vax[2] * vby[3] + vay[2] * vbx[3];
  t23x[2] = vbx[2] * vax[3] - vby[2] * vay[3]; t23y[2] = vbx[2] * vay[3] + vby[2] * vax[3];
  t23x[3] = vbx[2] * vbx[3] - vby[2] * vby[3]; t23y[3] = vbx[2] * vby[3] + vby[2] * vbx[3];
}

// phase 2: full product state, matvec with U, sign-sums
__device__ __forceinline__ void phase2(const float2* __restrict__ Uld,
                                       const float (&t01x)[4], const float (&t01y)[4],
                                       const float (&t23x)[4], const float (&t23y)[4],
                                       float (&ez)[4]) {
  float sx[16], sy[16];
#pragma unroll
  for (int i = 0; i < 16; ++i) {
    int a = i >> 2, c = i & 3;
    sx[i] = t01x[a] * t23x[c] - t01y[a] * t23y[c];
    sy[i] = t01x[a] * t23y[c] + t01y[a] * t23x[c];
  }
  float e0 = 0.f, e1 = 0.f, e2 = 0.f, e3 = 0.f;
#pragma unroll
  for (int i = 0; i < 16; ++i) {
    float ax = 0.f, ay = 0.f;
#pragma unroll
    for (int j = 0; j < 16; ++j) {
      float2 u = Uld[i * 16 + j];
      ax += u.x * sx[j] - u.y * sy[j];
      ay += u.x * sy[j] + u.y * sx[j];
    }
    float p = ax * ax + ay * ay;
    e0 += (i & 8) ? -p : p;
    e1 += (i & 4) ? -p : p;
    e2 += (i & 2) ? -p : p;
    e3 += (i & 1) ? -p : p;
  }
  ez[0] = e0; ez[1] = e1; ez[2] = e2; ez[3] = e3;
}

// ============ Kernel 1: U-build + encoder + matvec + partial sums ===========
__global__ __launch_bounds__(256) void fused_main_kernel(
    const float* __restrict__ features, const float* __restrict__ rand_params,
    const float* __restrict__ rx0, const float* __restrict__ ry0,
    const float* __restrict__ rz0, const float* __restrict__ crx0,
    float* __restrict__ ez_out, float* __restrict__ partials,
    float2* __restrict__ Uws, int B, int useEz) {
  __shared__ float2 ldsU[256];
  __shared__ float wred[4][8];
  int tid = threadIdx.x;
  long long b = (long long)blockIdx.x * 256 + tid;
  bool valid = b < B;

  // phase 1 for everyone (waves 1..3 proceed while wave 0 will build U)
  float t01x[4], t01y[4], t23x[4], t23y[4];
  if (valid) phase1(features, b, t01x, t01y, t23x, t23y);

  // wave-0 lanes 0..15 build U (straight-line constexpr gate chain)
  if (tid < 16) {
    float sx[16], sy[16];
#pragma unroll
    for (int i = 0; i < 16; ++i) { sx[i] = (i == tid) ? 1.f : 0.f; sy[i] = 0.f; }
    apply_gates<0>(sx, sy, rand_params, rx0, ry0, rz0, crx0);
#pragma unroll
    for (int i = 0; i < 16; ++i) {
      ldsU[i * 16 + tid] = make_float2(sx[i], sy[i]);
      if (!useEz && blockIdx.x == 0) Uws[i * 16 + tid] = make_float2(sx[i], sy[i]);
    }
  }
  __syncthreads();

  float ez[4] = {0.f, 0.f, 0.f, 0.f};
  if (valid) {
    phase2(ldsU, t01x, t01y, t23x, t23y, ez);
    if (useEz) ((float4*)ez_out)[b] = make_float4(ez[0], ez[1], ez[2], ez[3]);
  }
  float q[8] = {ez[0], ez[1], ez[2], ez[3],
                ez[0] * ez[0], ez[1] * ez[1], ez[2] * ez[2], ez[3] * ez[3]};
#pragma unroll
  for (int off = 32; off; off >>= 1)
#pragma unroll
    for (int k = 0; k < 8; ++k) q[k] += __shfl_down(q[k], off, 64);
  int lane = tid & 63, wv = tid >> 6;
  if (lane == 0)
#pragma unroll
    for (int k = 0; k < 8; ++k) wred[wv][k] = q[k];
  __syncthreads();
  if (tid == 0) {
#pragma unroll
    for (int k = 0; k < 8; ++k)
      partials[(size_t)blockIdx.x * 8 + k] =
          wred[0][k] + wred[1][k] + wred[2][k] + wred[3][k];
  }
}

// ========= Kernel 2: redundant stats reduce -> coef -> output pass ==========
__global__ __launch_bounds__(256) void out_kernel(
    const float* __restrict__ partials, int nblk,
    const float* __restrict__ gamma, const float* __restrict__ beta,
    const float* __restrict__ W, const float* __restrict__ bias,
    const float* __restrict__ ez_in, const float* __restrict__ features,
    const float2* __restrict__ Uws, float* __restrict__ out,
    int B, int useEz, float invB) {
  __shared__ float wred[4][8];
  __shared__ float coefs[5];
  __shared__ float2 ldsU[256];
  int tid = threadIdx.x;

  float q[8] = {0.f, 0.f, 0.f, 0.f, 0.f, 0.f, 0.f, 0.f};
  for (int idx = tid; idx < nblk; idx += 256) {
    const float4* p4 = (const float4*)(partials + (size_t)idx * 8);
    float4 A = p4[0], Bq = p4[1];
    q[0] += A.x;  q[1] += A.y;  q[2] += A.z;  q[3] += A.w;
    q[4] += Bq.x; q[5] += Bq.y; q[6] += Bq.z; q[7] += Bq.w;
  }
#pragma unroll
  for (int off = 32; off; off >>= 1)
#pragma unroll
    for (int k = 0; k < 8; ++k) q[k] += __shfl_down(q[k], off, 64);
  int lane = tid & 63, wv = tid >> 6;
  if (lane == 0)
#pragma unroll
    for (int k = 0; k < 8; ++k) wred[wv][k] = q[k];
  if (!useEz) ldsU[tid] = Uws[tid];
  __syncthreads();
  if (tid == 0) {
    float c0 = bias[0];
#pragma unroll
    for (int w = 0; w < 4; ++w) {
      float Sw = wred[0][w] + wred[1][w] + wred[2][w] + wred[3][w];
      float Qw = wred[0][4 + w] + wred[1][4 + w] + wred[2][4 + w] + wred[3][4 + w];
      float mu = Sw * invB;
      float var = Qw * invB - mu * mu;
      float inv = rsqrtf(var + 1e-5f);
      coefs[w] = W[w] * gamma[w] * inv;
      c0 += W[w] * (beta[w] - gamma[w] * mu * inv);
    }
    coefs[4] = c0;
  }
  __syncthreads();

  long long b = (long long)blockIdx.x * 256 + tid;
  if (b >= B) return;
  float ez[4];
  if (useEz) {
    float4 e = ((const float4*)ez_in)[b];
    ez[0] = e.x; ez[1] = e.y; ez[2] = e.z; ez[3] = e.w;
  } else {
    float t01x[4], t01y[4], t23x[4], t23y[4];
    phase1(features, b, t01x, t01y, t23x, t23y);
    phase2(ldsU, t01x, t01y, t23x, t23y, ez);
  }
  out[b] = coefs[4] + coefs[0] * ez[0] + coefs[1] * ez[1] +
           coefs[2] * ez[2] + coefs[3] * ez[3];
}

// ================================ launch ====================================
extern "C" void kernel_launch(void* const* d_in, const int* in_sizes, int n_in,
                              void* d_out, int out_size, void* d_ws, size_t ws_size,
                              hipStream_t stream) {
  const float* features    = (const float*)d_in[0];
  const float* rand_params = (const float*)d_in[1];
  const float* rx0         = (const float*)d_in[2];
  const float* ry0         = (const float*)d_in[3];
  const float* rz0         = (const float*)d_in[4];
  const float* crx0        = (const float*)d_in[5];
  const float* gamma       = (const float*)d_in[6];
  const float* beta        = (const float*)d_in[7];
  const float* W           = (const float*)d_in[8];
  const float* bias        = (const float*)d_in[9];
  float* out = (float*)d_out;

  int B = in_sizes[0] / 16;
  int nblk = (B + 255) / 256;

  char* ws = (char*)d_ws;
  float* partials = (float*)ws;                              // nblk*32 B
  size_t u_off = ((size_t)nblk * 32 + 255) & ~(size_t)255;
  float2* Uws = (float2*)(ws + u_off);                       // 2048 B (fallback)
  size_t ez_off = (u_off + 2048 + 255) & ~(size_t)255;
  float* ez = (float*)(ws + ez_off);
  int useEz = (ws_size >= ez_off + (size_t)B * 16) ? 1 : 0;

  fused_main_kernel<<<nblk, 256, 0, stream>>>(
      features, rand_params, rx0, ry0, rz0, crx0, ez, partials, Uws, B, useEz);
  out_kernel<<<nblk, 256, 0, stream>>>(
      partials, nblk, gamma, beta, W, bias, ez, features, Uws, out, B, useEz,
      1.0f / (float)B);
}